// Round 7
// baseline (410.227 us; speedup 1.0000x reference)
//
#include <hip/hip_runtime.h>
#include <math.h>

// Problem constants
#define Bb 2
#define Ll 2048
#define DMODEL 1024
#define DINNER 2048
#define DSTATE 8
#define DTRANK 64
#define DCONV 4
#define MM (Bb*Ll)          // 4096 rows
// scan chunking (CL=32 proven best)
#define NCH 64
#define CL 32               // NCH*CL == Ll
// G3 split-K
#define G3_KCH 8
#define G3_KC (DINNER / G3_KCH)   // 256

typedef __attribute__((ext_vector_type(8))) short    bf16x8;
typedef __attribute__((ext_vector_type(4))) float    f32x4;

__device__ __forceinline__ float silu_f(float x) {
    return x / (1.0f + __expf(-x));
}
__device__ __forceinline__ float softplus_f(float x) {
    return fmaxf(x, 0.0f) + log1pf(__expf(-fabsf(x)));
}
__device__ __forceinline__ unsigned short f2bf(float f) {
    unsigned int u = __float_as_uint(f);
    u += 0x7fffu + ((u >> 16) & 1u);      // RNE
    return (unsigned short)(u >> 16);
}
__device__ __forceinline__ float bf2f(unsigned short u) {
    return __uint_as_float(((unsigned int)u) << 16);
}
// async 16B global->LDS (wave-uniform LDS base + lane*16 dest)
__device__ __forceinline__ void async_cp16(const unsigned short* g, unsigned short* l) {
    __builtin_amdgcn_global_load_lds(
        (const __attribute__((address_space(1))) void*)g,
        (__attribute__((address_space(3))) void*)l, 16, 0, 0);
}

// ---------------------------------------------------------------------------
// bf16 MFMA GEMM (r11-proven): NW waves, tile 128 x TN, BK=32, double-
// buffered async staging, flat LDS + 16B-slot XOR swizzle -> 0 bank
// conflicts. ~650-670 TF plateau. Used for G4 (K=64) and G5.
// EPI: 0 none, 1 silu(x+bias[n]), 2 softplus(x+bias[n]).
// RX/RY XCD region swizzle; requires (gridDim.x/RX)*(gridDim.y/RY) == 8.
// ---------------------------------------------------------------------------
template <int EPI, int NW, int TN, typename OT, int RX = 0, int RY = 1>
__global__ __launch_bounds__(NW * 64, 4) void mfma_gemm(
    const unsigned short* __restrict__ A, const unsigned short* __restrict__ Bt,
    OT* __restrict__ C, OT* __restrict__ C2, int nsplit,
    int M, int N, int K, int lda, int ldb, int ldc,
    const float* __restrict__ bias)
{
    constexpr int NT   = NW * 64;     // threads
    constexpr int WNC  = NW / 2;      // waves along n
    constexpr int WNE  = TN / WNC;    // wave n-extent
    constexpr int NJ   = WNE / 16;    // b-frags per wave
    constexpr int RPP  = NT / 4;      // tile rows staged per pass
    constexpr int APASS = 128 / RPP;
    constexpr int BPASS = TN / RPP;

    __shared__ unsigned short As[2][128 * 32];
    __shared__ unsigned short Bs[2][TN * 32];

    int bxx = blockIdx.x, byy = blockIdx.y;
    if constexpr (RX > 0) {
        const int f = blockIdx.y * gridDim.x + blockIdx.x;
        const int c = f & 7, q = f >> 3;
        const int rgw = gridDim.x / RX;
        bxx = (c % rgw) * RX + (q % RX);
        byy = (c / rgw) * RY + (q / RX);
    }
    const int bm = byy * 128;
    const int bn = bxx * TN;
    const int tid  = threadIdx.x;
    const int w    = tid >> 6;
    const int lane = tid & 63;
    const int wm = (w / WNC) * 64;
    const int wn = (w % WNC) * WNE;
    const int lr = lane & 15;
    const int lq = lane >> 4;

    const int row  = tid >> 2;
    const int sp   = tid & 3;
    const int slog = sp ^ ((row >> 1) & 3);
    const unsigned short* gA = A  + (size_t)(bm + row) * lda + slog * 8;
    const unsigned short* gB = Bt + (size_t)(bn + row) * ldb + slog * 8;
    const int st = tid * 8;

    const int fsw = (lq ^ ((lr >> 1) & 3)) * 8;

    f32x4 acc[4][NJ];
#pragma unroll
    for (int i = 0; i < 4; ++i)
#pragma unroll
        for (int j = 0; j < NJ; ++j) acc[i][j] = (f32x4){0.f, 0.f, 0.f, 0.f};

#pragma unroll
    for (int p = 0; p < APASS; ++p)
        async_cp16(gA + (size_t)p * RPP * lda, &As[0][p * RPP * 32 + st]);
#pragma unroll
    for (int p = 0; p < BPASS; ++p)
        async_cp16(gB + (size_t)p * RPP * ldb, &Bs[0][p * RPP * 32 + st]);

    int cur = 0;
    for (int k0 = 0; k0 < K; k0 += 32, cur ^= 1) {
        __syncthreads();
        const int nk = k0 + 32;
        if (nk < K) {
            const int nb = cur ^ 1;
#pragma unroll
            for (int p = 0; p < APASS; ++p)
                async_cp16(gA + (size_t)p * RPP * lda + nk, &As[nb][p * RPP * 32 + st]);
#pragma unroll
            for (int p = 0; p < BPASS; ++p)
                async_cp16(gB + (size_t)p * RPP * ldb + nk, &Bs[nb][p * RPP * 32 + st]);
        }

        bf16x8 a[4], b[NJ];
#pragma unroll
        for (int i = 0; i < 4; ++i)
            a[i] = *(const bf16x8*)&As[cur][(wm + i * 16 + lr) * 32 + fsw];
#pragma unroll
        for (int j = 0; j < NJ; ++j)
            b[j] = *(const bf16x8*)&Bs[cur][(wn + j * 16 + lr) * 32 + fsw];
#pragma unroll
        for (int i = 0; i < 4; ++i)
#pragma unroll
            for (int j = 0; j < NJ; ++j)
                acc[i][j] = __builtin_amdgcn_mfma_f32_16x16x32_bf16(
                    a[i], b[j], acc[i][j], 0, 0, 0);
    }

#pragma unroll
    for (int i = 0; i < 4; ++i) {
        const int row0 = bm + wm + i * 16 + lq * 4;
#pragma unroll
        for (int j = 0; j < NJ; ++j) {
            const int col = bn + wn + j * 16 + lr;
            OT* Cb; int colb;
            if (col < nsplit) { Cb = C; colb = col; }
            else              { Cb = C2; colb = col - nsplit; }
            float bv = (EPI != 0) ? bias[col] : 0.0f;
#pragma unroll
            for (int r = 0; r < 4; ++r) {
                float v = acc[i][j][r];
                if (EPI == 1) v = silu_f(v + bv);
                if (EPI == 2) v = softplus_f(v + bv);
                if (sizeof(OT) == 2)
                    Cb[(size_t)(row0 + r) * ldc + colb] = (OT)f2bf(v);
                else
                    Cb[(size_t)(row0 + r) * ldc + colb] = (OT)v;
            }
        }
    }
}

// ---------------------------------------------------------------------------
// 256x256-tile deep-pipeline bf16 GEMM (G1). HW-VERIFIED r3/r6 (passed).
// Counted-vmcnt 4-phase schedule; FIFO trace in r1/r2 history.
// UNCHANGED this round (attribution discipline — only G2 changes in r7).
// ---------------------------------------------------------------------------
template <bool I1, bool I2, int VMA, int VMB>
__device__ __forceinline__ void g1_tile(
    int kt, const unsigned short* __restrict__ gA,
    const unsigned short* __restrict__ gB, int lda, int ldb,
    unsigned short* As, unsigned short* Bs, int st,
    int wm, int wn, int lr, int fsw, f32x4 (&acc)[8][4])
{
    const int cur = kt & 1;
    const int sb0 = (cur << 1) * 8192;
    const int sb1 = ((cur << 1) | 1) * 8192;
    const int nb1 = ((kt + 1) & 1) << 1;
    const int nb2 = ((kt + 2) & 1) << 1;
    bf16x8 a[4], b[4];

    // ---- phase 0: kh=0, mh=0 ----
#pragma unroll
    for (int i = 0; i < 4; ++i)
        a[i] = *(const bf16x8*)&As[sb0 + (wm + i * 16 + lr) * 32 + fsw];
#pragma unroll
    for (int j = 0; j < 4; ++j)
        b[j] = *(const bf16x8*)&Bs[sb0 + (wn + j * 16 + lr) * 32 + fsw];
    if (I1) {
        const unsigned short* s = gA + (kt + 1) * 64 + 32;
        unsigned short* d = &As[(nb1 | 1) * 8192 + st];
        async_cp16(s, d);
        async_cp16(s + (size_t)128 * lda, d + 4096);
        __builtin_amdgcn_sched_barrier(0);
    }
    __builtin_amdgcn_s_barrier();
    asm volatile("s_waitcnt lgkmcnt(0)" ::: "memory");
    __builtin_amdgcn_sched_barrier(0);
    __builtin_amdgcn_s_setprio(1);
#pragma unroll
    for (int i = 0; i < 4; ++i)
#pragma unroll
        for (int j = 0; j < 4; ++j)
            acc[i][j] = __builtin_amdgcn_mfma_f32_16x16x32_bf16(
                a[i], b[j], acc[i][j], 0, 0, 0);
    __builtin_amdgcn_s_setprio(0);
    __builtin_amdgcn_s_barrier();

    // ---- phase 1: kh=0, mh=1 ----
#pragma unroll
    for (int i = 0; i < 4; ++i)
        a[i] = *(const bf16x8*)&As[sb0 + (wm + (4 + i) * 16 + lr) * 32 + fsw];
    if (I1) {
        const unsigned short* s = gB + (kt + 1) * 64 + 32;
        unsigned short* d = &Bs[(nb1 | 1) * 8192 + st];
        async_cp16(s, d);
        async_cp16(s + (size_t)128 * ldb, d + 4096);
        __builtin_amdgcn_sched_barrier(0);
    }
    __builtin_amdgcn_s_barrier();
    asm volatile("s_waitcnt lgkmcnt(0)" ::: "memory");
    __builtin_amdgcn_sched_barrier(0);
    __builtin_amdgcn_s_setprio(1);
#pragma unroll
    for (int i = 0; i < 4; ++i)
#pragma unroll
        for (int j = 0; j < 4; ++j)
            acc[4 + i][j] = __builtin_amdgcn_mfma_f32_16x16x32_bf16(
                a[i], b[j], acc[4 + i][j], 0, 0, 0);
    __builtin_amdgcn_s_setprio(0);
    asm volatile("s_waitcnt vmcnt(%0)" :: "n"(VMA) : "memory");
    __builtin_amdgcn_s_barrier();

    // ---- phase 2: kh=1, mh=0 ----
#pragma unroll
    for (int i = 0; i < 4; ++i)
        a[i] = *(const bf16x8*)&As[sb1 + (wm + i * 16 + lr) * 32 + fsw];
#pragma unroll
    for (int j = 0; j < 4; ++j)
        b[j] = *(const bf16x8*)&Bs[sb1 + (wn + j * 16 + lr) * 32 + fsw];
    if (I2) {
        const unsigned short* s = gA + (kt + 2) * 64;
        unsigned short* d = &As[nb2 * 8192 + st];
        async_cp16(s, d);
        async_cp16(s + (size_t)128 * lda, d + 4096);
        __builtin_amdgcn_sched_barrier(0);
    }
    __builtin_amdgcn_s_barrier();
    asm volatile("s_waitcnt lgkmcnt(0)" ::: "memory");
    __builtin_amdgcn_sched_barrier(0);
    __builtin_amdgcn_s_setprio(1);
#pragma unroll
    for (int i = 0; i < 4; ++i)
#pragma unroll
        for (int j = 0; j < 4; ++j)
            acc[i][j] = __builtin_amdgcn_mfma_f32_16x16x32_bf16(
                a[i], b[j], acc[i][j], 0, 0, 0);
    __builtin_amdgcn_s_setprio(0);
    __builtin_amdgcn_s_barrier();

    // ---- phase 3: kh=1, mh=1 ----
#pragma unroll
    for (int i = 0; i < 4; ++i)
        a[i] = *(const bf16x8*)&As[sb1 + (wm + (4 + i) * 16 + lr) * 32 + fsw];
    if (I2) {
        const unsigned short* s = gB + (kt + 2) * 64;
        unsigned short* d = &Bs[nb2 * 8192 + st];
        async_cp16(s, d);
        async_cp16(s + (size_t)128 * ldb, d + 4096);
        __builtin_amdgcn_sched_barrier(0);
    }
    __builtin_amdgcn_s_barrier();
    asm volatile("s_waitcnt lgkmcnt(0)" ::: "memory");
    __builtin_amdgcn_sched_barrier(0);
    __builtin_amdgcn_s_setprio(1);
#pragma unroll
    for (int i = 0; i < 4; ++i)
#pragma unroll
        for (int j = 0; j < 4; ++j)
            acc[4 + i][j] = __builtin_amdgcn_mfma_f32_16x16x32_bf16(
                a[i], b[j], acc[4 + i][j], 0, 0, 0);
    __builtin_amdgcn_s_setprio(0);
    asm volatile("s_waitcnt vmcnt(%0)" :: "n"(VMB) : "memory");
    __builtin_amdgcn_s_barrier();
}

__global__ __launch_bounds__(512, 2) void gemm256_g1(
    const unsigned short* __restrict__ A, const unsigned short* __restrict__ Bt,
    unsigned short* __restrict__ Cx, unsigned short* __restrict__ Cz,
    int K, int lda, int ldb, int ldc, int nsplit)
{
    __shared__ unsigned short As[4 * 8192];   // 64 KB
    __shared__ unsigned short Bs[4 * 8192];   // 64 KB

    int bx, by;
    {
        const int f = blockIdx.y * gridDim.x + blockIdx.x;
        const int c = f & 7, q = f >> 3;
        const int rgw = gridDim.x >> 3;
        bx = (c % rgw) * 8 + (q & 7);
        by = (c / rgw) * 4 + (q >> 3);
    }
    const int bm = by * 256, bn = bx * 256;
    const int tid  = threadIdx.x;
    const int lane = tid & 63;
    const int w    = tid >> 6;
    const int wm = (w >> 2) << 7;
    const int wn = (w & 3) << 6;
    const int lr = lane & 15;
    const int lq = lane >> 4;
    const int fsw = (lq ^ ((lr >> 1) & 3)) * 8;

    const int row  = tid >> 2;
    const int slog = (tid & 3) ^ ((row >> 1) & 3);
    const unsigned short* gA = A  + (size_t)(bm + row) * lda + slog * 8;
    const unsigned short* gB = Bt + (size_t)(bn + row) * ldb + slog * 8;
    const int st = tid * 8;
    const int NT = K >> 6;

    f32x4 acc[8][4];
#pragma unroll
    for (int i = 0; i < 8; ++i)
#pragma unroll
        for (int j = 0; j < 4; ++j) acc[i][j] = (f32x4){0.f, 0.f, 0.f, 0.f};

    auto stg = [&](const unsigned short* g, int ld, unsigned short* d) {
        async_cp16(g, d);
        async_cp16(g + (size_t)128 * ld, d + 4096);
    };
    stg(gA,      lda, As + 0 * 8192 + st);
    __builtin_amdgcn_sched_barrier(0);
    stg(gB,      ldb, Bs + 0 * 8192 + st);
    __builtin_amdgcn_sched_barrier(0);
    stg(gA + 32, lda, As + 1 * 8192 + st);
    __builtin_amdgcn_sched_barrier(0);
    stg(gB + 32, ldb, Bs + 1 * 8192 + st);
    __builtin_amdgcn_sched_barrier(0);
    stg(gA + 64, lda, As + 2 * 8192 + st);
    __builtin_amdgcn_sched_barrier(0);
    stg(gB + 64, ldb, Bs + 2 * 8192 + st);
    asm volatile("s_waitcnt vmcnt(8)" ::: "memory");
    __builtin_amdgcn_sched_barrier(0);
    __builtin_amdgcn_s_barrier();

    for (int kt = 0; kt + 2 < NT; ++kt)
        g1_tile<true, true, 8, 8>(kt, gA, gB, lda, ldb,
                                  As, Bs, st, wm, wn, lr, fsw, acc);
    g1_tile<true,  false, 8, 4>(NT - 2, gA, gB, lda, ldb,
                                As, Bs, st, wm, wn, lr, fsw, acc);
    g1_tile<false, false, 0, 0>(NT - 1, gA, gB, lda, ldb,
                                As, Bs, st, wm, wn, lr, fsw, acc);

#pragma unroll
    for (int i = 0; i < 8; ++i) {
        const int row0 = bm + wm + i * 16 + lq * 4;
#pragma unroll
        for (int j = 0; j < 4; ++j) {
            const int col = bn + wn + j * 16 + lr;
            unsigned short* Cb; int colb;
            if (col < nsplit) { Cb = Cx; colb = col; }
            else              { Cb = Cz; colb = col - nsplit; }
#pragma unroll
            for (int r = 0; r < 4; ++r)
                Cb[(size_t)(row0 + r) * ldc + colb] = f2bf(acc[i][j][r]);
        }
    }
}

// ---------------------------------------------------------------------------
// NEW r7: G2 256M x 128N, 3-BUFFER, ONE barrier + ONE vmcnt PER K-TILE.
// r6 post-mortem: the 2-phase lockstep (4 sync points/K-tile) landed at
// 695 TF / MfmaUtil 27% — 1852 cyc/phase of which only ~500 MFMA. The
// barriers force all 8 waves to serialize {ds_read drain} with {MFMA}
// every 16 MFMA. Fix: 3 LDS buffers make the mid-tile barriers UNNECESSARY:
//   - intra-tile: all waves read buf kt%3 (read-read, safe); staging
//     targets buf (kt+2)%3 != kt%3 (no collision with current reads).
//   - WAR: buf (kt+2)%3 == buf (kt-1)%3, whose last reads were drained by
//     each wave's OWN lgkmcnt(0) before its MFMA in tile kt-1, all
//     sequenced before the single end-of-tile barrier. Staging in tile kt
//     comes after that barrier -> safe.
//   - landed-guarantee: end-of-tile-kt vmcnt(6)+barrier proves T_{kt+1}
//     (both halves) complete in ALL waves before tile kt+1 reads it.
// FIFO trace (3 cp16/group; groups T_jh0, T_jh1 in order):
//   prologue: T0h0,T0h1,T1h0,T1h1 = 12 instrs; vmcnt(6) -> T0 landed.
//   tile kt (kt<=NT-3) issues T_{kt+2}h0 (+3), T_{kt+2}h1 (+3);
//   end-tile-kt issued = 12+6(kt+1); vmcnt(6) -> done thru instr 6kt+12
//   = group 2kt+4 = T_{kt+1}h1. EXACTLY next tile's data.
//   tile NT-2: no stage; issued = 6NT; T_{NT-1}h1 ends at 6NT -> vmcnt(0).
//   tile NT-1: nothing outstanding; no vmcnt, no barrier.
// Waves drift freely within a tile: one wave's 16-MFMA cluster overlaps
// another's ds_reads — restores the cross-wave overlap that 4-block
// occupancy used to provide. 32 MFMA per sync point (was 16 per 2).
// LDS: As 3x2x16KB=96KB + Bs 3x2x8KB=48KB = 144KB -> 1 block/CU.
// Requires K mult 64, NT>=3, M mult 256, N mult 128.
// ---------------------------------------------------------------------------
template <bool STG, int VM>
__device__ __forceinline__ void g2b_tile(
    int kt, const unsigned short* __restrict__ gA,
    const unsigned short* __restrict__ gB, int lda, int ldb,
    unsigned short* As, unsigned short* Bs, int st,
    int wm, int wn, int lr, int fsw, f32x4 (&acc)[4][4])
{
    const int buf  = kt % 3;
    const int buf2 = (kt + 2) % 3;          // staging target buffer
    unsigned short* A0 = As + (buf * 2 + 0) * 8192;
    unsigned short* A1 = As + (buf * 2 + 1) * 8192;
    unsigned short* B0 = Bs + (buf * 2 + 0) * 4096;
    unsigned short* B1 = Bs + (buf * 2 + 1) * 4096;
    bf16x8 a[4], b[4];

    // ---- half 0 (kh=0) ----
#pragma unroll
    for (int i = 0; i < 4; ++i)
        a[i] = *(const bf16x8*)&A0[(wm + i * 16 + lr) * 32 + fsw];
#pragma unroll
    for (int j = 0; j < 4; ++j)
        b[j] = *(const bf16x8*)&B0[(wn + j * 16 + lr) * 32 + fsw];
    if (STG) {   // stage T_{kt+2} kh0: A(2) + B(1)
        const unsigned short* sA = gA + (kt + 2) * 64;
        unsigned short* dA = As + (buf2 * 2 + 0) * 8192 + st;
        async_cp16(sA, dA);
        async_cp16(sA + (size_t)128 * lda, dA + 4096);
        async_cp16(gB + (kt + 2) * 64, Bs + (buf2 * 2 + 0) * 4096 + st);
        __builtin_amdgcn_sched_barrier(0);
    }
    asm volatile("s_waitcnt lgkmcnt(0)" ::: "memory");
    __builtin_amdgcn_sched_barrier(0);
    __builtin_amdgcn_s_setprio(1);
#pragma unroll
    for (int i = 0; i < 4; ++i)
#pragma unroll
        for (int j = 0; j < 4; ++j)
            acc[i][j] = __builtin_amdgcn_mfma_f32_16x16x32_bf16(
                a[i], b[j], acc[i][j], 0, 0, 0);
    __builtin_amdgcn_s_setprio(0);

    // ---- half 1 (kh=1) — no barrier between halves ----
#pragma unroll
    for (int i = 0; i < 4; ++i)
        a[i] = *(const bf16x8*)&A1[(wm + i * 16 + lr) * 32 + fsw];
#pragma unroll
    for (int j = 0; j < 4; ++j)
        b[j] = *(const bf16x8*)&B1[(wn + j * 16 + lr) * 32 + fsw];
    if (STG) {   // stage T_{kt+2} kh1
        const unsigned short* sA = gA + (kt + 2) * 64 + 32;
        unsigned short* dA = As + (buf2 * 2 + 1) * 8192 + st;
        async_cp16(sA, dA);
        async_cp16(sA + (size_t)128 * lda, dA + 4096);
        async_cp16(gB + (kt + 2) * 64 + 32, Bs + (buf2 * 2 + 1) * 4096 + st);
        __builtin_amdgcn_sched_barrier(0);
    }
    asm volatile("s_waitcnt lgkmcnt(0)" ::: "memory");
    __builtin_amdgcn_sched_barrier(0);
    __builtin_amdgcn_s_setprio(1);
#pragma unroll
    for (int i = 0; i < 4; ++i)
#pragma unroll
        for (int j = 0; j < 4; ++j)
            acc[i][j] = __builtin_amdgcn_mfma_f32_16x16x32_bf16(
                a[i], b[j], acc[i][j], 0, 0, 0);
    __builtin_amdgcn_s_setprio(0);

    if constexpr (VM >= 0) {
        asm volatile("s_waitcnt vmcnt(%0)" :: "n"(VM) : "memory");
        __builtin_amdgcn_s_barrier();
    }
}

template <int EPI, typename OT>
__global__ __launch_bounds__(512, 2) void gemm256x128(
    const unsigned short* __restrict__ A, const unsigned short* __restrict__ Bt,
    OT* __restrict__ C, int K, int lda, int ldb, int ldc,
    const float* __restrict__ bias)
{
    __shared__ unsigned short As[6 * 8192];   // 3 bufs x 2 kh x 16KB = 96 KB
    __shared__ unsigned short Bs[6 * 4096];   // 3 bufs x 2 kh x 8KB  = 48 KB

    // XCD region swizzle (grid 16x16): 8 regions of 8x4
    int bx, by;
    {
        const int f = blockIdx.y * gridDim.x + blockIdx.x;
        const int c = f & 7, q = f >> 3;
        const int rgw = gridDim.x >> 3;       // = 2
        bx = (c % rgw) * 8 + (q & 7);
        by = (c / rgw) * 4 + (q >> 3);
    }
    const int bm = by * 256, bn = bx * 128;
    const int tid  = threadIdx.x;
    const int lane = tid & 63;
    const int w    = tid >> 6;
    const int wm = (w >> 1) << 6;             // 0,64,128,192
    const int wn = (w & 1) << 6;              // 0,64
    const int lr = lane & 15;
    const int lq = lane >> 4;
    const int fsw = (lq ^ ((lr >> 1) & 3)) * 8;

    // staging: thread t -> row t>>2 (A: +128 on 2nd instr), slot t&3
    const int row  = tid >> 2;
    const int slog = (tid & 3) ^ ((row >> 1) & 3);
    const unsigned short* gA = A  + (size_t)(bm + row) * lda + slog * 8;
    const unsigned short* gB = Bt + (size_t)(bn + row) * ldb + slog * 8;
    const int st = tid * 8;
    const int NT = K >> 6;                    // requires >= 3

    f32x4 acc[4][4];
#pragma unroll
    for (int i = 0; i < 4; ++i)
#pragma unroll
        for (int j = 0; j < 4; ++j) acc[i][j] = (f32x4){0.f, 0.f, 0.f, 0.f};

    // prologue: T0h0,T0h1 -> buf0; T1h0,T1h1 -> buf1 (order pinned)
    auto stg = [&](int ko, int slot) {
        const unsigned short* sA = gA + ko;
        unsigned short* dA = As + slot * 8192 + st;
        async_cp16(sA, dA);
        async_cp16(sA + (size_t)128 * lda, dA + 4096);
        async_cp16(gB + ko, Bs + slot * 4096 + st);
    };
    stg(0, 0);
    __builtin_amdgcn_sched_barrier(0);
    stg(32, 1);
    __builtin_amdgcn_sched_barrier(0);
    stg(64, 2);
    __builtin_amdgcn_sched_barrier(0);
    stg(96, 3);
    asm volatile("s_waitcnt vmcnt(6)" ::: "memory");   // T0 (h0+h1) landed
    __builtin_amdgcn_sched_barrier(0);
    __builtin_amdgcn_s_barrier();

    for (int kt = 0; kt < NT - 2; ++kt)
        g2b_tile<true, 6>(kt, gA, gB, lda, ldb,
                          As, Bs, st, wm, wn, lr, fsw, acc);
    g2b_tile<false, 0>(NT - 2, gA, gB, lda, ldb,
                       As, Bs, st, wm, wn, lr, fsw, acc);
    g2b_tile<false, -1>(NT - 1, gA, gB, lda, ldb,
                        As, Bs, st, wm, wn, lr, fsw, acc);

    // epilogue: C/D layout col = lane&15, row = (lane>>4)*4 + reg
#pragma unroll
    for (int i = 0; i < 4; ++i) {
        const int row0 = bm + wm + i * 16 + lq * 4;
#pragma unroll
        for (int j = 0; j < 4; ++j) {
            const int col = bn + wn + j * 16 + lr;
            float bv = (EPI != 0) ? bias[col] : 0.0f;
#pragma unroll
            for (int r = 0; r < 4; ++r) {
                float v = acc[i][j][r];
                if (EPI == 1) v = silu_f(v + bv);
                if (EPI == 2) v = softplus_f(v + bv);
                if (sizeof(OT) == 2)
                    C[(size_t)(row0 + r) * ldc + col] = (OT)f2bf(v);
                else
                    C[(size_t)(row0 + r) * ldc + col] = (OT)v;
            }
        }
    }
}

// ---------------------------------------------------------------------------
// prep_all: ONE kernel for input cast + 4 weight transpose-casts.
// ---------------------------------------------------------------------------
__global__ __launch_bounds__(256) void prep_all(
    const float* __restrict__ x, const float* __restrict__ W_in,
    const float* __restrict__ pwk, const float* __restrict__ W_out,
    const float* __restrict__ W_dt,
    unsigned short* __restrict__ x_bf, unsigned short* __restrict__ Wint,
    unsigned short* __restrict__ pw_t, unsigned short* __restrict__ Woutt,
    unsigned short* __restrict__ Wdtt)
{
    const int b = blockIdx.x;
    const int t = threadIdx.x;
    if (b < 4096) {                       // cast
        int i = b * 1024 + t * 4;
        float4 v = *(const float4*)&x[i];
        ushort4 o;
        o.x = f2bf(v.x); o.y = f2bf(v.y); o.z = f2bf(v.z); o.w = f2bf(v.w);
        *(ushort4*)&x_bf[i] = o;
        return;
    }
    const float* src; unsigned short* dst; int R, C, c0, r0;
    if (b < 8192) {
        int bi = b - 4096; src = W_in; dst = Wint; R = 1024; C = 4096;
        c0 = (bi & 127) * 32; r0 = (bi >> 7) * 32;
    } else if (b < 12288) {
        int bi = b - 8192; src = pwk; dst = pw_t; R = 2048; C = 2048;
        c0 = (bi & 63) * 32; r0 = (bi >> 6) * 32;
    } else if (b < 14336) {
        int bi = b - 12288; src = W_out; dst = Woutt; R = 2048; C = 1024;
        c0 = (bi & 31) * 32; r0 = (bi >> 5) * 32;
    } else {
        int bi = b - 14336; src = W_dt; dst = Wdtt; R = 64; C = 2048;
        c0 = (bi & 63) * 32; r0 = (bi >> 6) * 32;
    }
    __shared__ float tile[32][33];
    const int tx = t & 31;
    const int ty = t >> 5;
#pragma unroll
    for (int i = 0; i < 32; i += 8)
        tile[ty + i][tx] = src[(size_t)(r0 + ty + i) * C + c0 + tx];
    __syncthreads();
#pragma unroll
    for (int i = 0; i < 32; i += 8)
        dst[(size_t)(c0 + ty + i) * R + r0 + tx] = f2bf(tile[tx][ty + i]);
}

// ---------------------------------------------------------------------------
// G3 split-K: part[kc][M][80] = xc_bf[:, kc*256:(kc+1)*256] @ W_x-chunk
// ---------------------------------------------------------------------------
__global__ __launch_bounds__(256) void g3_splitk(
    const unsigned short* __restrict__ xc, const float* __restrict__ Wx,
    float* __restrict__ part)
{
    __shared__ float As[16][68];
    __shared__ float Bs[16][85];
    const int m0 = blockIdx.x * 64;
    const int kb = blockIdx.y * G3_KC;
    const int t = threadIdx.x;
    const int tr = t >> 4;
    const int tc = t & 15;

    const int arow = t >> 2;
    const int ak4  = (t & 3) * 4;
    const int bk   = t >> 4;
    const int bc   = (t & 15) * 5;

    float acc[4][5];
#pragma unroll
    for (int r = 0; r < 4; ++r)
#pragma unroll
        for (int c = 0; c < 5; ++c) acc[r][c] = 0.0f;

    for (int k0 = 0; k0 < G3_KC; k0 += 16) {
        ushort4 av = *(const ushort4*)&xc[(size_t)(m0 + arow) * DINNER + kb + k0 + ak4];
        float bv[5];
#pragma unroll
        for (int q = 0; q < 5; ++q)
            bv[q] = Wx[(size_t)(kb + k0 + bk) * 80 + bc + q];
        __syncthreads();
        As[ak4 + 0][arow] = bf2f(av.x);
        As[ak4 + 1][arow] = bf2f(av.y);
        As[ak4 + 2][arow] = bf2f(av.z);
        As[ak4 + 3][arow] = bf2f(av.w);
#pragma unroll
        for (int q = 0; q < 5; ++q) Bs[bk][bc + q] = bv[q];
        __syncthreads();
#pragma unroll
        for (int k = 0; k < 16; ++k) {
            float a[4], b[5];
#pragma unroll
            for (int r = 0; r < 4; ++r) a[r] = As[k][tr * 4 + r];
#pragma unroll
            for (int c = 0; c < 5; ++c) b[c] = Bs[k][tc * 5 + c];
#pragma unroll
            for (int r = 0; r < 4; ++r)
#pragma unroll
                for (int c = 0; c < 5; ++c)
                    acc[r][c] = fmaf(a[r], b[c], acc[r][c]);
        }
    }
#pragma unroll
    for (int r = 0; r < 4; ++r)
#pragma unroll
        for (int c = 0; c < 5; ++c)
            part[((size_t)blockIdx.y * MM + m0 + tr * 4 + r) * 80 + tc * 5 + c] = acc[r][c];
}

// reduce 8 partials -> xdbl fp32 AND bf16 delta cols [M][64] for G4.
__global__ __launch_bounds__(256) void g3_reduce(
    const float* __restrict__ part, float* __restrict__ xdbl,
    unsigned short* __restrict__ xdbl64)
{
    int i = (blockIdx.x * 256 + threadIdx.x) * 4;
    if (i >= MM * 80) return;
    float4 s = *(const float4*)&part[i];
#pragma unroll
    for (int c = 1; c < G3_KCH; ++c) {
        float4 p = *(const float4*)&part[(size_t)c * MM * 80 + i];
        s.x += p.x; s.y += p.y; s.z += p.z; s.w += p.w;
    }
    *(float4*)&xdbl[i] = s;
    int col = i % 80;
    if (col < 64) {
        int row = i / 80;
        ushort4 o;
        o.x = f2bf(s.x); o.y = f2bf(s.y); o.z = f2bf(s.z); o.w = f2bf(s.w);
        *(ushort4*)&xdbl64[(size_t)row * 64 + col] = o;
    }
}

// ---------------------------------------------------------------------------
// Depthwise causal conv on dense bf16 x_in [M][DINNER]; bf16 out; x4 vector.
// ---------------------------------------------------------------------------
__global__ __launch_bounds__(256) void dwconv_kernel(
    const unsigned short* __restrict__ x_in, const float* __restrict__ dwk,
    unsigned short* __restrict__ out)
{
    int i4 = blockIdx.x * 256 + threadIdx.x;
    if (i4 >= MM * DINNER / 4) return;
    int d = (i4 * 4) & (DINNER - 1);
    int bl = (i4 * 4) >> 11;
    int l = bl & (Ll - 1);
    int b = bl >> 11;
    float a0 = 0.f, a1 = 0.f, a2 = 0.f, a3 = 0.f;
#pragma unroll
    for (int k = 0; k < DCONV; ++k) {
        int t = l + k - (DCONV - 1);
        if (t >= 0) {
            ushort4 xv = *(const ushort4*)&x_in[(size_t)(b * Ll + t) * DINNER + d];
            float4 wv = *(const float4*)&dwk[k * DINNER + d];
            a0 = fmaf(bf2f(xv.x), wv.x, a0);
            a1 = fmaf(bf2f(xv.y), wv.y, a1);
            a2 = fmaf(bf2f(xv.z), wv.z, a2);
            a3 = fmaf(bf2f(xv.w), wv.w, a3);
        }
    }
    ushort4 o;
    o.x = f2bf(a0); o.y = f2bf(a1); o.z = f2bf(a2); o.w = f2bf(a3);
    *(ushort4*)&out[i4 * 4] = o;
}

// ---------------------------------------------------------------------------
// Selective scan pass 1: per-chunk local scan from h=0. xc is bf16.
// ---------------------------------------------------------------------------
__global__ __launch_bounds__(256) void scan_pass1(
    const float* __restrict__ delta, const unsigned short* __restrict__ xc,
    const float* __restrict__ xdbl, const float* __restrict__ A_log,
    float* __restrict__ cs_a, float* __restrict__ cs_h)
{
    const int d = blockIdx.x * 256 + threadIdx.x;
    const int c = blockIdx.y;
    const int b = blockIdx.z;
    const int t0 = c * CL;

    __shared__ float sB[CL][8];
    {
        int i = threadIdx.x;
        int t = i >> 3, j = i & 7;
        sB[t][j] = xdbl[((size_t)(b * Ll + t0 + t)) * 80 + DTRANK + j];
    }
    __syncthreads();

    float An[8];
#pragma unroll
    for (int n = 0; n < 8; ++n) An[n] = -__expf(A_log[d * 8 + n]);

    float h[8], ap[8];
#pragma unroll
    for (int n = 0; n < 8; ++n) { h[n] = 0.0f; ap[n] = 1.0f; }

    const float* dptr = delta + ((size_t)(b * Ll + t0)) * DINNER + d;
    const unsigned short* xptr = xc + ((size_t)(b * Ll + t0)) * DINNER + d;

#pragma unroll 4
    for (int t = 0; t < CL; ++t) {
        float dl = dptr[(size_t)t * DINNER];
        float xv = bf2f(xptr[(size_t)t * DINNER]);
        float du = dl * xv;
#pragma unroll
        for (int n = 0; n < 8; ++n) {
            float dA = __expf(dl * An[n]);
            h[n] = fmaf(dA, h[n], du * sB[t][n]);
            ap[n] *= dA;
        }
    }

    size_t base = (((size_t)(b * NCH + c)) * 8) * DINNER + d;
#pragma unroll
    for (int n = 0; n < 8; ++n) {
        cs_a[base + (size_t)n * DINNER] = ap[n];
        cs_h[base + (size_t)n * DINNER] = h[n];
    }
}

// Pass 2: sequential combine; hin ALIASES cs_h (in-place) — read-before-write.
__global__ __launch_bounds__(256) void scan_pass2(
    const float* __restrict__ cs_a, const float* cs_h, float* hin)
{
    int idx = blockIdx.x * 256 + threadIdx.x;
    if (idx >= Bb * 8 * DINNER) return;
    int d = idx & (DINNER - 1);
    int n = (idx >> 11) & 7;
    int b = idx >> 14;
    float H = 0.0f;
#pragma unroll 4
    for (int c = 0; c < NCH; ++c) {
        size_t o = (((size_t)(b * NCH + c)) * 8 + n) * DINNER + d;
        float a = cs_a[o];
        float hh = cs_h[o];
        hin[o] = H;
        H = fmaf(a, H, hh);
    }
}

// Pass 3: replay with correct h_in; fused epilogue -> bf16 y. z dense bf16.
__global__ __launch_bounds__(256) void scan_pass3(
    const float* __restrict__ delta, const unsigned short* __restrict__ xc,
    const float* __restrict__ xdbl, const float* __restrict__ A_log,
    const float* __restrict__ hin, const unsigned short* __restrict__ z,
    const float* __restrict__ Dvec, unsigned short* __restrict__ y_bf)
{
    const int d = blockIdx.x * 256 + threadIdx.x;
    const int c = blockIdx.y;
    const int b = blockIdx.z;
    const int t0 = c * CL;

    __shared__ float sB[CL][8];
    __shared__ float sC[CL][8];
    {
        int i = threadIdx.x;
        int t = i >> 4, j = i & 15;
        float v = xdbl[((size_t)(b * Ll + t0 + t)) * 80 + DTRANK + j];
        if (j < 8) sB[t][j] = v; else sC[t][j - 8] = v;
        t = (i + 256) >> 4; j = (i + 256) & 15;
        v = xdbl[((size_t)(b * Ll + t0 + t)) * 80 + DTRANK + j];
        if (j < 8) sB[t][j] = v; else sC[t][j - 8] = v;
    }
    __syncthreads();

    float An[8];
#pragma unroll
    for (int n = 0; n < 8; ++n) An[n] = -__expf(A_log[d * 8 + n]);

    float h[8];
    size_t hbase = (((size_t)(b * NCH + c)) * 8) * DINNER + d;
#pragma unroll
    for (int n = 0; n < 8; ++n) h[n] = hin[hbase + (size_t)n * DINNER];

    const float Dd = Dvec[d];
    const float* dptr = delta + ((size_t)(b * Ll + t0)) * DINNER + d;
    const unsigned short* xptr = xc + ((size_t)(b * Ll + t0)) * DINNER + d;
    const unsigned short* zptr = z + ((size_t)(b * Ll + t0)) * DINNER + d;
    unsigned short* yptr = y_bf + ((size_t)(b * Ll + t0)) * DINNER + d;

    for (int t = 0; t < CL; ++t) {
        float dl = dptr[(size_t)t * DINNER];
        float xv = bf2f(xptr[(size_t)t * DINNER]);
        float du = dl * xv;
        float yt = 0.0f;
#pragma unroll
        for (int n = 0; n < 8; ++n) {
            float dA = __expf(dl * An[n]);
            h[n] = fmaf(dA, h[n], du * sB[t][n]);
            yt = fmaf(sC[t][n], h[n], yt);
        }
        float zv = bf2f(zptr[(size_t)t * DINNER]);
        yptr[(size_t)t * DINNER] = f2bf((yt + xv * Dd) * silu_f(zv));
    }
}

// ---------------------------------------------------------------------------
extern "C" void kernel_launch(void* const* d_in, const int* in_sizes, int n_in,
                              void* d_out, int out_size, void* d_ws, size_t ws_size,
                              hipStream_t stream)
{
    const float* x         = (const float*)d_in[0];
    const float* W_in      = (const float*)d_in[1];
    const float* dwk       = (const float*)d_in[2];
    const float* pwk       = (const float*)d_in[3];
    const float* conv_bias = (const float*)d_in[4];
    const float* W_x       = (const float*)d_in[5];
    const float* W_dt      = (const float*)d_in[6];
    const float* b_dt      = (const float*)d_in[7];
    const float* A_log     = (const float*)d_in[8];
    const float* Dv        = (const float*)d_in[9];
    const float* W_out     = (const float*)d_in[10];
    float* out = (float*)d_out;

    // workspace map (MiB offsets; peak 152.25 MiB <= proven 154)
    char* ws = (char*)d_ws;
    unsigned short* x_in_bf = (unsigned short*)(ws);                  // [0,16)   G1..conv
    unsigned short* z_bf    = (unsigned short*)(ws + (16ull << 20));  // [16,32)  G1..p3
    float*          delta   = (float*)(ws + (32ull << 20));           // [32,64)  G4..p3
    unsigned short* x_bf    = (unsigned short*)(ws + (64ull << 20));  // [64,72)  prep..G1
    unsigned short* y_bf    = (unsigned short*)(ws + (64ull << 20));  // [64,80)  p3..G5
    unsigned short* Wint    = (unsigned short*)(ws + (72ull << 20));  // [72,80)  prep..G1
    unsigned short* pw_t    = (unsigned short*)(ws + (80ull << 20));  // [80,88)  prep..G2
    unsigned short* xcp_bf  = (unsigned short*)(ws + (88ull << 20));  // [88,104) conv..G2
    unsigned short* xc_bf   = (unsigned short*)(ws + (104ull << 20)); // [104,120) G2..p3
    unsigned short* Woutt   = (unsigned short*)(ws + (120ull << 20)); // [120,124) prep..G5
    float*          xdbl    = (float*)(ws + (124ull << 20));          // [124,125.25) g3red..p3
    unsigned short* xdbl64  = (unsigned short*)(ws + (125ull << 20) + (512ull << 10)); // 0.5 MB
    float*          g3part  = (float*)(ws + (126ull << 20));          // [126,136) g3..g3red
    float*          cs_a    = (float*)(ws + (136ull << 20));          // [136,144) p1..p2
    float*          cs_h    = (float*)(ws + (144ull << 20));          // [144,152) p1..p3
    unsigned short* Wdtt    = (unsigned short*)(ws + (152ull << 20)); // 0.25 MB, prep..G4
    float*          hin     = cs_h;   // in-place
    dim3 blk(256);

    // prep: cast + 4 transposes fused into one dispatch
    prep_all<<<14464, blk, 0, stream>>>(x, W_in, pwk, W_out, W_dt,
                                        x_bf, Wint, pw_t, Woutt, Wdtt);

    // G1: xz = x @ W_in, deinterleaved bf16 (x_in | z). 256^2-tile
    // deep-pipeline kernel (HW-verified r3/r6), grid 16x16 = 1/CU.
    gemm256_g1<<<dim3((2 * DINNER) / 256, MM / 256), dim3(512), 0, stream>>>(
        x_bf, Wint, x_in_bf, z_bf,
        /*K*/DMODEL, /*lda*/DMODEL, /*ldb*/DMODEL, /*ldc*/DINNER,
        /*nsplit*/DINNER);

    // depthwise causal conv (bf16 in, bf16 out)
    dwconv_kernel<<<MM * DINNER / 4 / 256, blk, 0, stream>>>(x_in_bf, dwk, xcp_bf);

    // G2: xc = silu(conv @ pw + conv_bias) -> bf16. NEW r7: 3-buffer,
    // ONE barrier + ONE vmcnt per K-tile (was 49.4us / MfmaUtil 27% with
    // 4 sync points per tile; predicted ~30us).
    gemm256x128<1, unsigned short>
        <<<dim3(DINNER / 128, MM / 256), dim3(512), 0, stream>>>(
        xcp_bf, pw_t, xc_bf,
        /*K*/DINNER, /*lda*/DINNER, /*ldb*/DINNER, /*ldc*/DINNER, conv_bias);

    // G3: x_dbl partials = xc @ W_x (split-K fp32) + materialized reduce
    g3_splitk<<<dim3(MM / 64, G3_KCH), blk, 0, stream>>>(xc_bf, W_x, g3part);
    g3_reduce<<<(MM * 80 / 4 + 255) / 256, blk, 0, stream>>>(g3part, xdbl, xdbl64);

    // G4: delta = softplus(xdbl64 @ Wdtt^T + b_dt) — MFMA, K=64 (2 iters).
    mfma_gemm<2, 4, 128, float, 8, 8>
        <<<dim3(DINNER / 128, MM / 128), blk, 0, stream>>>(
        xdbl64, Wdtt, delta, delta, DINNER + 1,
        MM, DINNER, DTRANK, DTRANK, DTRANK, DINNER, b_dt);

    // selective scan, 3-pass chunked (CL=32, NCH=64 — proven)
    scan_pass1<<<dim3(DINNER / 256, NCH, Bb), blk, 0, stream>>>(
        delta, xc_bf, xdbl, A_log, cs_a, cs_h);
    scan_pass2<<<(Bb * 8 * DINNER + 255) / 256, blk, 0, stream>>>(cs_a, cs_h, hin);
    scan_pass3<<<dim3(DINNER / 256, NCH, Bb), blk, 0, stream>>>(
        delta, xc_bf, xdbl, A_log, hin, z_bf, Dv, y_bf);

    // G5: out = y @ W_out. NW=4, TN=64 -> 512 blocks, direct write,
    // + XCD region swizzle.
    mfma_gemm<0, 4, 64, float, 8, 8>
        <<<dim3(DMODEL / 64, MM / 128), blk, 0, stream>>>(
        y_bf, Woutt, out, out, DMODEL + 1,
        MM, DMODEL, DINNER, DINNER, DINNER, DMODEL, nullptr);
}

// Round 8
// 360.407 us; speedup vs baseline: 1.1382x; 1.1382x over previous
//
#include <hip/hip_runtime.h>
#include <math.h>

// Problem constants
#define Bb 2
#define Ll 2048
#define DMODEL 1024
#define DINNER 2048
#define DSTATE 8
#define DTRANK 64
#define DCONV 4
#define MM (Bb*Ll)          // 4096 rows
// scan chunking (CL=32 proven best)
#define NCH 64
#define CL 32               // NCH*CL == Ll
// G3 split-K
#define G3_KCH 8
#define G3_KC (DINNER / G3_KCH)   // 256

typedef __attribute__((ext_vector_type(8))) short    bf16x8;
typedef __attribute__((ext_vector_type(4))) float    f32x4;

__device__ __forceinline__ float silu_f(float x) {
    return x / (1.0f + __expf(-x));
}
__device__ __forceinline__ float softplus_f(float x) {
    return fmaxf(x, 0.0f) + log1pf(__expf(-fabsf(x)));
}
__device__ __forceinline__ unsigned short f2bf(float f) {
    unsigned int u = __float_as_uint(f);
    u += 0x7fffu + ((u >> 16) & 1u);      // RNE
    return (unsigned short)(u >> 16);
}
__device__ __forceinline__ float bf2f(unsigned short u) {
    return __uint_as_float(((unsigned int)u) << 16);
}
// async 16B global->LDS (wave-uniform LDS base + lane*16 dest)
__device__ __forceinline__ void async_cp16(const unsigned short* g, unsigned short* l) {
    __builtin_amdgcn_global_load_lds(
        (const __attribute__((address_space(1))) void*)g,
        (__attribute__((address_space(3))) void*)l, 16, 0, 0);
}

// ---------------------------------------------------------------------------
// bf16 MFMA GEMM (r11-proven): NW waves, tile 128 x TN, BK=32, double-
// buffered async staging, flat LDS + 16B-slot XOR swizzle -> 0 bank
// conflicts. Used for G4 (r8: TN=64, 1024 blocks = 4/CU — r7 profile showed
// G4 memory-bound, MfmaUtil 0.4%, stores at 356 GB/s; more resident blocks
// overlap store bursts) and G5 (TN=64, proven).
// EPI: 0 none, 1 silu(x+bias[n]), 2 softplus(x+bias[n]).
// RX/RY XCD region swizzle; requires (gridDim.x/RX)*(gridDim.y/RY) == 8.
// ---------------------------------------------------------------------------
template <int EPI, int NW, int TN, typename OT, int RX = 0, int RY = 1>
__global__ __launch_bounds__(NW * 64, 4) void mfma_gemm(
    const unsigned short* __restrict__ A, const unsigned short* __restrict__ Bt,
    OT* __restrict__ C, OT* __restrict__ C2, int nsplit,
    int M, int N, int K, int lda, int ldb, int ldc,
    const float* __restrict__ bias)
{
    constexpr int NT   = NW * 64;     // threads
    constexpr int WNC  = NW / 2;      // waves along n
    constexpr int WNE  = TN / WNC;    // wave n-extent
    constexpr int NJ   = WNE / 16;    // b-frags per wave
    constexpr int RPP  = NT / 4;      // tile rows staged per pass
    constexpr int APASS = 128 / RPP;
    constexpr int BPASS = TN / RPP;

    __shared__ unsigned short As[2][128 * 32];
    __shared__ unsigned short Bs[2][TN * 32];

    int bxx = blockIdx.x, byy = blockIdx.y;
    if constexpr (RX > 0) {
        const int f = blockIdx.y * gridDim.x + blockIdx.x;
        const int c = f & 7, q = f >> 3;
        const int rgw = gridDim.x / RX;
        bxx = (c % rgw) * RX + (q % RX);
        byy = (c / rgw) * RY + (q / RX);
    }
    const int bm = byy * 128;
    const int bn = bxx * TN;
    const int tid  = threadIdx.x;
    const int w    = tid >> 6;
    const int lane = tid & 63;
    const int wm = (w / WNC) * 64;
    const int wn = (w % WNC) * WNE;
    const int lr = lane & 15;
    const int lq = lane >> 4;

    const int row  = tid >> 2;
    const int sp   = tid & 3;
    const int slog = sp ^ ((row >> 1) & 3);
    const unsigned short* gA = A  + (size_t)(bm + row) * lda + slog * 8;
    const unsigned short* gB = Bt + (size_t)(bn + row) * ldb + slog * 8;
    const int st = tid * 8;

    const int fsw = (lq ^ ((lr >> 1) & 3)) * 8;

    f32x4 acc[4][NJ];
#pragma unroll
    for (int i = 0; i < 4; ++i)
#pragma unroll
        for (int j = 0; j < NJ; ++j) acc[i][j] = (f32x4){0.f, 0.f, 0.f, 0.f};

#pragma unroll
    for (int p = 0; p < APASS; ++p)
        async_cp16(gA + (size_t)p * RPP * lda, &As[0][p * RPP * 32 + st]);
#pragma unroll
    for (int p = 0; p < BPASS; ++p)
        async_cp16(gB + (size_t)p * RPP * ldb, &Bs[0][p * RPP * 32 + st]);

    int cur = 0;
    for (int k0 = 0; k0 < K; k0 += 32, cur ^= 1) {
        __syncthreads();
        const int nk = k0 + 32;
        if (nk < K) {
            const int nb = cur ^ 1;
#pragma unroll
            for (int p = 0; p < APASS; ++p)
                async_cp16(gA + (size_t)p * RPP * lda + nk, &As[nb][p * RPP * 32 + st]);
#pragma unroll
            for (int p = 0; p < BPASS; ++p)
                async_cp16(gB + (size_t)p * RPP * ldb + nk, &Bs[nb][p * RPP * 32 + st]);
        }

        bf16x8 a[4], b[NJ];
#pragma unroll
        for (int i = 0; i < 4; ++i)
            a[i] = *(const bf16x8*)&As[cur][(wm + i * 16 + lr) * 32 + fsw];
#pragma unroll
        for (int j = 0; j < NJ; ++j)
            b[j] = *(const bf16x8*)&Bs[cur][(wn + j * 16 + lr) * 32 + fsw];
#pragma unroll
        for (int i = 0; i < 4; ++i)
#pragma unroll
            for (int j = 0; j < NJ; ++j)
                acc[i][j] = __builtin_amdgcn_mfma_f32_16x16x32_bf16(
                    a[i], b[j], acc[i][j], 0, 0, 0);
    }

#pragma unroll
    for (int i = 0; i < 4; ++i) {
        const int row0 = bm + wm + i * 16 + lq * 4;
#pragma unroll
        for (int j = 0; j < NJ; ++j) {
            const int col = bn + wn + j * 16 + lr;
            OT* Cb; int colb;
            if (col < nsplit) { Cb = C; colb = col; }
            else              { Cb = C2; colb = col - nsplit; }
            float bv = (EPI != 0) ? bias[col] : 0.0f;
#pragma unroll
            for (int r = 0; r < 4; ++r) {
                float v = acc[i][j][r];
                if (EPI == 1) v = silu_f(v + bv);
                if (EPI == 2) v = softplus_f(v + bv);
                if (sizeof(OT) == 2)
                    Cb[(size_t)(row0 + r) * ldc + colb] = (OT)f2bf(v);
                else
                    Cb[(size_t)(row0 + r) * ldc + colb] = (OT)v;
            }
        }
    }
}

// ---------------------------------------------------------------------------
// 256x256-tile deep-pipeline bf16 GEMM (G1). HW-VERIFIED r3/r6 (passed).
// Counted-vmcnt 4-phase schedule; FIFO trace in r1/r2 history. UNCHANGED.
// ---------------------------------------------------------------------------
template <bool I1, bool I2, int VMA, int VMB>
__device__ __forceinline__ void g1_tile(
    int kt, const unsigned short* __restrict__ gA,
    const unsigned short* __restrict__ gB, int lda, int ldb,
    unsigned short* As, unsigned short* Bs, int st,
    int wm, int wn, int lr, int fsw, f32x4 (&acc)[8][4])
{
    const int cur = kt & 1;
    const int sb0 = (cur << 1) * 8192;
    const int sb1 = ((cur << 1) | 1) * 8192;
    const int nb1 = ((kt + 1) & 1) << 1;
    const int nb2 = ((kt + 2) & 1) << 1;
    bf16x8 a[4], b[4];

    // ---- phase 0: kh=0, mh=0 ----
#pragma unroll
    for (int i = 0; i < 4; ++i)
        a[i] = *(const bf16x8*)&As[sb0 + (wm + i * 16 + lr) * 32 + fsw];
#pragma unroll
    for (int j = 0; j < 4; ++j)
        b[j] = *(const bf16x8*)&Bs[sb0 + (wn + j * 16 + lr) * 32 + fsw];
    if (I1) {
        const unsigned short* s = gA + (kt + 1) * 64 + 32;
        unsigned short* d = &As[(nb1 | 1) * 8192 + st];
        async_cp16(s, d);
        async_cp16(s + (size_t)128 * lda, d + 4096);
        __builtin_amdgcn_sched_barrier(0);
    }
    __builtin_amdgcn_s_barrier();
    asm volatile("s_waitcnt lgkmcnt(0)" ::: "memory");
    __builtin_amdgcn_sched_barrier(0);
    __builtin_amdgcn_s_setprio(1);
#pragma unroll
    for (int i = 0; i < 4; ++i)
#pragma unroll
        for (int j = 0; j < 4; ++j)
            acc[i][j] = __builtin_amdgcn_mfma_f32_16x16x32_bf16(
                a[i], b[j], acc[i][j], 0, 0, 0);
    __builtin_amdgcn_s_setprio(0);
    __builtin_amdgcn_s_barrier();

    // ---- phase 1: kh=0, mh=1 ----
#pragma unroll
    for (int i = 0; i < 4; ++i)
        a[i] = *(const bf16x8*)&As[sb0 + (wm + (4 + i) * 16 + lr) * 32 + fsw];
    if (I1) {
        const unsigned short* s = gB + (kt + 1) * 64 + 32;
        unsigned short* d = &Bs[(nb1 | 1) * 8192 + st];
        async_cp16(s, d);
        async_cp16(s + (size_t)128 * ldb, d + 4096);
        __builtin_amdgcn_sched_barrier(0);
    }
    __builtin_amdgcn_s_barrier();
    asm volatile("s_waitcnt lgkmcnt(0)" ::: "memory");
    __builtin_amdgcn_sched_barrier(0);
    __builtin_amdgcn_s_setprio(1);
#pragma unroll
    for (int i = 0; i < 4; ++i)
#pragma unroll
        for (int j = 0; j < 4; ++j)
            acc[4 + i][j] = __builtin_amdgcn_mfma_f32_16x16x32_bf16(
                a[i], b[j], acc[4 + i][j], 0, 0, 0);
    __builtin_amdgcn_s_setprio(0);
    asm volatile("s_waitcnt vmcnt(%0)" :: "n"(VMA) : "memory");
    __builtin_amdgcn_s_barrier();

    // ---- phase 2: kh=1, mh=0 ----
#pragma unroll
    for (int i = 0; i < 4; ++i)
        a[i] = *(const bf16x8*)&As[sb1 + (wm + i * 16 + lr) * 32 + fsw];
#pragma unroll
    for (int j = 0; j < 4; ++j)
        b[j] = *(const bf16x8*)&Bs[sb1 + (wn + j * 16 + lr) * 32 + fsw];
    if (I2) {
        const unsigned short* s = gA + (kt + 2) * 64;
        unsigned short* d = &As[nb2 * 8192 + st];
        async_cp16(s, d);
        async_cp16(s + (size_t)128 * lda, d + 4096);
        __builtin_amdgcn_sched_barrier(0);
    }
    __builtin_amdgcn_s_barrier();
    asm volatile("s_waitcnt lgkmcnt(0)" ::: "memory");
    __builtin_amdgcn_sched_barrier(0);
    __builtin_amdgcn_s_setprio(1);
#pragma unroll
    for (int i = 0; i < 4; ++i)
#pragma unroll
        for (int j = 0; j < 4; ++j)
            acc[i][j] = __builtin_amdgcn_mfma_f32_16x16x32_bf16(
                a[i], b[j], acc[i][j], 0, 0, 0);
    __builtin_amdgcn_s_setprio(0);
    __builtin_amdgcn_s_barrier();

    // ---- phase 3: kh=1, mh=1 ----
#pragma unroll
    for (int i = 0; i < 4; ++i)
        a[i] = *(const bf16x8*)&As[sb1 + (wm + (4 + i) * 16 + lr) * 32 + fsw];
    if (I2) {
        const unsigned short* s = gB + (kt + 2) * 64;
        unsigned short* d = &Bs[nb2 * 8192 + st];
        async_cp16(s, d);
        async_cp16(s + (size_t)128 * ldb, d + 4096);
        __builtin_amdgcn_sched_barrier(0);
    }
    __builtin_amdgcn_s_barrier();
    asm volatile("s_waitcnt lgkmcnt(0)" ::: "memory");
    __builtin_amdgcn_sched_barrier(0);
    __builtin_amdgcn_s_setprio(1);
#pragma unroll
    for (int i = 0; i < 4; ++i)
#pragma unroll
        for (int j = 0; j < 4; ++j)
            acc[4 + i][j] = __builtin_amdgcn_mfma_f32_16x16x32_bf16(
                a[i], b[j], acc[4 + i][j], 0, 0, 0);
    __builtin_amdgcn_s_setprio(0);
    asm volatile("s_waitcnt vmcnt(%0)" :: "n"(VMB) : "memory");
    __builtin_amdgcn_s_barrier();
}

__global__ __launch_bounds__(512, 2) void gemm256_g1(
    const unsigned short* __restrict__ A, const unsigned short* __restrict__ Bt,
    unsigned short* __restrict__ Cx, unsigned short* __restrict__ Cz,
    int K, int lda, int ldb, int ldc, int nsplit)
{
    __shared__ unsigned short As[4 * 8192];   // 64 KB
    __shared__ unsigned short Bs[4 * 8192];   // 64 KB

    int bx, by;
    {
        const int f = blockIdx.y * gridDim.x + blockIdx.x;
        const int c = f & 7, q = f >> 3;
        const int rgw = gridDim.x >> 3;
        bx = (c % rgw) * 8 + (q & 7);
        by = (c / rgw) * 4 + (q >> 3);
    }
    const int bm = by * 256, bn = bx * 256;
    const int tid  = threadIdx.x;
    const int lane = tid & 63;
    const int w    = tid >> 6;
    const int wm = (w >> 2) << 7;
    const int wn = (w & 3) << 6;
    const int lr = lane & 15;
    const int lq = lane >> 4;
    const int fsw = (lq ^ ((lr >> 1) & 3)) * 8;

    const int row  = tid >> 2;
    const int slog = (tid & 3) ^ ((row >> 1) & 3);
    const unsigned short* gA = A  + (size_t)(bm + row) * lda + slog * 8;
    const unsigned short* gB = Bt + (size_t)(bn + row) * ldb + slog * 8;
    const int st = tid * 8;
    const int NT = K >> 6;

    f32x4 acc[8][4];
#pragma unroll
    for (int i = 0; i < 8; ++i)
#pragma unroll
        for (int j = 0; j < 4; ++j) acc[i][j] = (f32x4){0.f, 0.f, 0.f, 0.f};

    auto stg = [&](const unsigned short* g, int ld, unsigned short* d) {
        async_cp16(g, d);
        async_cp16(g + (size_t)128 * ld, d + 4096);
    };
    stg(gA,      lda, As + 0 * 8192 + st);
    __builtin_amdgcn_sched_barrier(0);
    stg(gB,      ldb, Bs + 0 * 8192 + st);
    __builtin_amdgcn_sched_barrier(0);
    stg(gA + 32, lda, As + 1 * 8192 + st);
    __builtin_amdgcn_sched_barrier(0);
    stg(gB + 32, ldb, Bs + 1 * 8192 + st);
    __builtin_amdgcn_sched_barrier(0);
    stg(gA + 64, lda, As + 2 * 8192 + st);
    __builtin_amdgcn_sched_barrier(0);
    stg(gB + 64, ldb, Bs + 2 * 8192 + st);
    asm volatile("s_waitcnt vmcnt(8)" ::: "memory");
    __builtin_amdgcn_sched_barrier(0);
    __builtin_amdgcn_s_barrier();

    for (int kt = 0; kt + 2 < NT; ++kt)
        g1_tile<true, true, 8, 8>(kt, gA, gB, lda, ldb,
                                  As, Bs, st, wm, wn, lr, fsw, acc);
    g1_tile<true,  false, 8, 4>(NT - 2, gA, gB, lda, ldb,
                                As, Bs, st, wm, wn, lr, fsw, acc);
    g1_tile<false, false, 0, 0>(NT - 1, gA, gB, lda, ldb,
                                As, Bs, st, wm, wn, lr, fsw, acc);

#pragma unroll
    for (int i = 0; i < 8; ++i) {
        const int row0 = bm + wm + i * 16 + lq * 4;
#pragma unroll
        for (int j = 0; j < 4; ++j) {
            const int col = bn + wn + j * 16 + lr;
            unsigned short* Cb; int colb;
            if (col < nsplit) { Cb = Cx; colb = col; }
            else              { Cb = Cz; colb = col - nsplit; }
#pragma unroll
            for (int r = 0; r < 4; ++r)
                Cb[(size_t)(row0 + r) * ldc + colb] = f2bf(acc[i][j][r]);
        }
    }
}

// ---------------------------------------------------------------------------
// G2: 256M x 128N deep-pipeline bf16 GEMM — r6 VERSION RESTORED (HW-verified
// 49.4us, total 362.8). r7's 3-buffer barrier-free variant REVERTED: it
// regressed total to 410us with an anomalous 2x slowdown of the unchanged
// G4 kernel (suspect clock/adjacency or co-compile perturbation, rule #19).
// 2 phases/K-tile, counted vmcnt(6); FIFO trace in r3-r5 history.
// ---------------------------------------------------------------------------
template <bool I1, bool I2, int VMA, int VMB>
__device__ __forceinline__ void g2_tile(
    int kt, const unsigned short* __restrict__ gA,
    const unsigned short* __restrict__ gB, int lda, int ldb,
    unsigned short* As, unsigned short* Bs, int st,
    int wm, int wn, int lr, int fsw, f32x4 (&acc)[4][4])
{
    const int cur = kt & 1;
    const int sa0 = (cur << 1) * 8192;
    const int sa1 = ((cur << 1) | 1) * 8192;
    const int sb0 = (cur << 1) * 4096;
    const int sb1 = ((cur << 1) | 1) * 4096;
    const int nb1 = (((kt + 1) & 1) << 1) | 1;
    const int nb2 = ((kt + 2) & 1) << 1;
    bf16x8 a[4], b[4];

    // ---- phase 0: kh=0 ----
#pragma unroll
    for (int i = 0; i < 4; ++i)
        a[i] = *(const bf16x8*)&As[sa0 + (wm + i * 16 + lr) * 32 + fsw];
#pragma unroll
    for (int j = 0; j < 4; ++j)
        b[j] = *(const bf16x8*)&Bs[sb0 + (wn + j * 16 + lr) * 32 + fsw];
    if (I1) {
        const unsigned short* sA = gA + (kt + 1) * 64 + 32;
        unsigned short* dA = &As[nb1 * 8192 + st];
        async_cp16(sA, dA);
        async_cp16(sA + (size_t)128 * lda, dA + 4096);
        async_cp16(gB + (kt + 1) * 64 + 32, &Bs[nb1 * 4096 + st]);
        __builtin_amdgcn_sched_barrier(0);
    }
    __builtin_amdgcn_s_barrier();
    asm volatile("s_waitcnt lgkmcnt(0)" ::: "memory");
    __builtin_amdgcn_sched_barrier(0);
    __builtin_amdgcn_s_setprio(1);
#pragma unroll
    for (int i = 0; i < 4; ++i)
#pragma unroll
        for (int j = 0; j < 4; ++j)
            acc[i][j] = __builtin_amdgcn_mfma_f32_16x16x32_bf16(
                a[i], b[j], acc[i][j], 0, 0, 0);
    __builtin_amdgcn_s_setprio(0);
    asm volatile("s_waitcnt vmcnt(%0)" :: "n"(VMA) : "memory");
    __builtin_amdgcn_s_barrier();

    // ---- phase 1: kh=1 ----
#pragma unroll
    for (int i = 0; i < 4; ++i)
        a[i] = *(const bf16x8*)&As[sa1 + (wm + i * 16 + lr) * 32 + fsw];
#pragma unroll
    for (int j = 0; j < 4; ++j)
        b[j] = *(const bf16x8*)&Bs[sb1 + (wn + j * 16 + lr) * 32 + fsw];
    if (I2) {
        const unsigned short* sA = gA + (kt + 2) * 64;
        unsigned short* dA = &As[nb2 * 8192 + st];
        async_cp16(sA, dA);
        async_cp16(sA + (size_t)128 * lda, dA + 4096);
        async_cp16(gB + (kt + 2) * 64, &Bs[nb2 * 4096 + st]);
        __builtin_amdgcn_sched_barrier(0);
    }
    __builtin_amdgcn_s_barrier();
    asm volatile("s_waitcnt lgkmcnt(0)" ::: "memory");
    __builtin_amdgcn_sched_barrier(0);
    __builtin_amdgcn_s_setprio(1);
#pragma unroll
    for (int i = 0; i < 4; ++i)
#pragma unroll
        for (int j = 0; j < 4; ++j)
            acc[i][j] = __builtin_amdgcn_mfma_f32_16x16x32_bf16(
                a[i], b[j], acc[i][j], 0, 0, 0);
    __builtin_amdgcn_s_setprio(0);
    asm volatile("s_waitcnt vmcnt(%0)" :: "n"(VMB) : "memory");
    __builtin_amdgcn_s_barrier();
}

template <int EPI, typename OT>
__global__ __launch_bounds__(512, 2) void gemm256x128(
    const unsigned short* __restrict__ A, const unsigned short* __restrict__ Bt,
    OT* __restrict__ C, int K, int lda, int ldb, int ldc,
    const float* __restrict__ bias)
{
    __shared__ unsigned short As[4 * 8192];   // [buf][kh] 256x32 = 64 KB
    __shared__ unsigned short Bs[4 * 4096];   // [buf][kh] 128x32 = 32 KB

    // XCD region swizzle (grid 16x16): 8 regions of 8x4
    int bx, by;
    {
        const int f = blockIdx.y * gridDim.x + blockIdx.x;
        const int c = f & 7, q = f >> 3;
        const int rgw = gridDim.x >> 3;       // = 2
        bx = (c % rgw) * 8 + (q & 7);
        by = (c / rgw) * 4 + (q >> 3);
    }
    const int bm = by * 256, bn = bx * 128;
    const int tid  = threadIdx.x;
    const int lane = tid & 63;
    const int w    = tid >> 6;
    const int wm = (w >> 1) << 6;             // 0,64,128,192
    const int wn = (w & 1) << 6;              // 0,64
    const int lr = lane & 15;
    const int lq = lane >> 4;
    const int fsw = (lq ^ ((lr >> 1) & 3)) * 8;

    const int row  = tid >> 2;
    const int slog = (tid & 3) ^ ((row >> 1) & 3);
    const unsigned short* gA = A  + (size_t)(bm + row) * lda + slog * 8;
    const unsigned short* gB = Bt + (size_t)(bn + row) * ldb + slog * 8;
    const int st = tid * 8;
    const int NT = K >> 6;                    // requires >= 3

    f32x4 acc[4][4];
#pragma unroll
    for (int i = 0; i < 4; ++i)
#pragma unroll
        for (int j = 0; j < 4; ++j) acc[i][j] = (f32x4){0.f, 0.f, 0.f, 0.f};

    // prologue: kh0(0) -> slot0, kh1(0) -> slot1, kh0(1) -> slot2; pinned
    auto stg = [&](int ko, int slot) {
        const unsigned short* sA = gA + ko;
        unsigned short* dA = &As[slot * 8192 + st];
        async_cp16(sA, dA);
        async_cp16(sA + (size_t)128 * lda, dA + 4096);
        async_cp16(gB + ko, &Bs[slot * 4096 + st]);
    };
    stg(0, 0);
    __builtin_amdgcn_sched_barrier(0);
    stg(32, 1);
    __builtin_amdgcn_sched_barrier(0);
    stg(64, 2);
    asm volatile("s_waitcnt vmcnt(6)" ::: "memory");   // kh0(0) landed
    __builtin_amdgcn_sched_barrier(0);
    __builtin_amdgcn_s_barrier();

    for (int kt = 0; kt + 2 < NT; ++kt)
        g2_tile<true, true, 6, 6>(kt, gA, gB, lda, ldb,
                                  As, Bs, st, wm, wn, lr, fsw, acc);
    g2_tile<true,  false, 6, 3>(NT - 2, gA, gB, lda, ldb,
                                As, Bs, st, wm, wn, lr, fsw, acc);
    g2_tile<false, false, 0, 0>(NT - 1, gA, gB, lda, ldb,
                                As, Bs, st, wm, wn, lr, fsw, acc);

    // epilogue: C/D layout col = lane&15, row = (lane>>4)*4 + reg
#pragma unroll
    for (int i = 0; i < 4; ++i) {
        const int row0 = bm + wm + i * 16 + lq * 4;
#pragma unroll
        for (int j = 0; j < 4; ++j) {
            const int col = bn + wn + j * 16 + lr;
            float bv = (EPI != 0) ? bias[col] : 0.0f;
#pragma unroll
            for (int r = 0; r < 4; ++r) {
                float v = acc[i][j][r];
                if (EPI == 1) v = silu_f(v + bv);
                if (EPI == 2) v = softplus_f(v + bv);
                if (sizeof(OT) == 2)
                    C[(size_t)(row0 + r) * ldc + col] = (OT)f2bf(v);
                else
                    C[(size_t)(row0 + r) * ldc + col] = (OT)v;
            }
        }
    }
}

// ---------------------------------------------------------------------------
// prep_all: ONE kernel for input cast + 4 weight transpose-casts.
// ---------------------------------------------------------------------------
__global__ __launch_bounds__(256) void prep_all(
    const float* __restrict__ x, const float* __restrict__ W_in,
    const float* __restrict__ pwk, const float* __restrict__ W_out,
    const float* __restrict__ W_dt,
    unsigned short* __restrict__ x_bf, unsigned short* __restrict__ Wint,
    unsigned short* __restrict__ pw_t, unsigned short* __restrict__ Woutt,
    unsigned short* __restrict__ Wdtt)
{
    const int b = blockIdx.x;
    const int t = threadIdx.x;
    if (b < 4096) {                       // cast
        int i = b * 1024 + t * 4;
        float4 v = *(const float4*)&x[i];
        ushort4 o;
        o.x = f2bf(v.x); o.y = f2bf(v.y); o.z = f2bf(v.z); o.w = f2bf(v.w);
        *(ushort4*)&x_bf[i] = o;
        return;
    }
    const float* src; unsigned short* dst; int R, C, c0, r0;
    if (b < 8192) {
        int bi = b - 4096; src = W_in; dst = Wint; R = 1024; C = 4096;
        c0 = (bi & 127) * 32; r0 = (bi >> 7) * 32;
    } else if (b < 12288) {
        int bi = b - 8192; src = pwk; dst = pw_t; R = 2048; C = 2048;
        c0 = (bi & 63) * 32; r0 = (bi >> 6) * 32;
    } else if (b < 14336) {
        int bi = b - 12288; src = W_out; dst = Woutt; R = 2048; C = 1024;
        c0 = (bi & 31) * 32; r0 = (bi >> 5) * 32;
    } else {
        int bi = b - 14336; src = W_dt; dst = Wdtt; R = 64; C = 2048;
        c0 = (bi & 63) * 32; r0 = (bi >> 6) * 32;
    }
    __shared__ float tile[32][33];
    const int tx = t & 31;
    const int ty = t >> 5;
#pragma unroll
    for (int i = 0; i < 32; i += 8)
        tile[ty + i][tx] = src[(size_t)(r0 + ty + i) * C + c0 + tx];
    __syncthreads();
#pragma unroll
    for (int i = 0; i < 32; i += 8)
        dst[(size_t)(c0 + ty + i) * R + r0 + tx] = f2bf(tile[tx][ty + i]);
}

// ---------------------------------------------------------------------------
// G3 split-K: part[kc][M][80] = xc_bf[:, kc*256:(kc+1)*256] @ W_x-chunk
// ---------------------------------------------------------------------------
__global__ __launch_bounds__(256) void g3_splitk(
    const unsigned short* __restrict__ xc, const float* __restrict__ Wx,
    float* __restrict__ part)
{
    __shared__ float As[16][68];
    __shared__ float Bs[16][85];
    const int m0 = blockIdx.x * 64;
    const int kb = blockIdx.y * G3_KC;
    const int t = threadIdx.x;
    const int tr = t >> 4;
    const int tc = t & 15;

    const int arow = t >> 2;
    const int ak4  = (t & 3) * 4;
    const int bk   = t >> 4;
    const int bc   = (t & 15) * 5;

    float acc[4][5];
#pragma unroll
    for (int r = 0; r < 4; ++r)
#pragma unroll
        for (int c = 0; c < 5; ++c) acc[r][c] = 0.0f;

    for (int k0 = 0; k0 < G3_KC; k0 += 16) {
        ushort4 av = *(const ushort4*)&xc[(size_t)(m0 + arow) * DINNER + kb + k0 + ak4];
        float bv[5];
#pragma unroll
        for (int q = 0; q < 5; ++q)
            bv[q] = Wx[(size_t)(kb + k0 + bk) * 80 + bc + q];
        __syncthreads();
        As[ak4 + 0][arow] = bf2f(av.x);
        As[ak4 + 1][arow] = bf2f(av.y);
        As[ak4 + 2][arow] = bf2f(av.z);
        As[ak4 + 3][arow] = bf2f(av.w);
#pragma unroll
        for (int q = 0; q < 5; ++q) Bs[bk][bc + q] = bv[q];
        __syncthreads();
#pragma unroll
        for (int k = 0; k < 16; ++k) {
            float a[4], b[5];
#pragma unroll
            for (int r = 0; r < 4; ++r) a[r] = As[k][tr * 4 + r];
#pragma unroll
            for (int c = 0; c < 5; ++c) b[c] = Bs[k][tc * 5 + c];
#pragma unroll
            for (int r = 0; r < 4; ++r)
#pragma unroll
                for (int c = 0; c < 5; ++c)
                    acc[r][c] = fmaf(a[r], b[c], acc[r][c]);
        }
    }
#pragma unroll
    for (int r = 0; r < 4; ++r)
#pragma unroll
        for (int c = 0; c < 5; ++c)
            part[((size_t)blockIdx.y * MM + m0 + tr * 4 + r) * 80 + tc * 5 + c] = acc[r][c];
}

// reduce 8 partials -> xdbl fp32 AND bf16 delta cols [M][64] for G4.
__global__ __launch_bounds__(256) void g3_reduce(
    const float* __restrict__ part, float* __restrict__ xdbl,
    unsigned short* __restrict__ xdbl64)
{
    int i = (blockIdx.x * 256 + threadIdx.x) * 4;
    if (i >= MM * 80) return;
    float4 s = *(const float4*)&part[i];
#pragma unroll
    for (int c = 1; c < G3_KCH; ++c) {
        float4 p = *(const float4*)&part[(size_t)c * MM * 80 + i];
        s.x += p.x; s.y += p.y; s.z += p.z; s.w += p.w;
    }
    *(float4*)&xdbl[i] = s;
    int col = i % 80;
    if (col < 64) {
        int row = i / 80;
        ushort4 o;
        o.x = f2bf(s.x); o.y = f2bf(s.y); o.z = f2bf(s.z); o.w = f2bf(s.w);
        *(ushort4*)&xdbl64[(size_t)row * 64 + col] = o;
    }
}

// ---------------------------------------------------------------------------
// Depthwise causal conv on dense bf16 x_in [M][DINNER]; bf16 out; x4 vector.
// ---------------------------------------------------------------------------
__global__ __launch_bounds__(256) void dwconv_kernel(
    const unsigned short* __restrict__ x_in, const float* __restrict__ dwk,
    unsigned short* __restrict__ out)
{
    int i4 = blockIdx.x * 256 + threadIdx.x;
    if (i4 >= MM * DINNER / 4) return;
    int d = (i4 * 4) & (DINNER - 1);
    int bl = (i4 * 4) >> 11;
    int l = bl & (Ll - 1);
    int b = bl >> 11;
    float a0 = 0.f, a1 = 0.f, a2 = 0.f, a3 = 0.f;
#pragma unroll
    for (int k = 0; k < DCONV; ++k) {
        int t = l + k - (DCONV - 1);
        if (t >= 0) {
            ushort4 xv = *(const ushort4*)&x_in[(size_t)(b * Ll + t) * DINNER + d];
            float4 wv = *(const float4*)&dwk[k * DINNER + d];
            a0 = fmaf(bf2f(xv.x), wv.x, a0);
            a1 = fmaf(bf2f(xv.y), wv.y, a1);
            a2 = fmaf(bf2f(xv.z), wv.z, a2);
            a3 = fmaf(bf2f(xv.w), wv.w, a3);
        }
    }
    ushort4 o;
    o.x = f2bf(a0); o.y = f2bf(a1); o.z = f2bf(a2); o.w = f2bf(a3);
    *(ushort4*)&out[i4 * 4] = o;
}

// ---------------------------------------------------------------------------
// Selective scan pass 1: per-chunk local scan from h=0. xc is bf16.
// ---------------------------------------------------------------------------
__global__ __launch_bounds__(256) void scan_pass1(
    const float* __restrict__ delta, const unsigned short* __restrict__ xc,
    const float* __restrict__ xdbl, const float* __restrict__ A_log,
    float* __restrict__ cs_a, float* __restrict__ cs_h)
{
    const int d = blockIdx.x * 256 + threadIdx.x;
    const int c = blockIdx.y;
    const int b = blockIdx.z;
    const int t0 = c * CL;

    __shared__ float sB[CL][8];
    {
        int i = threadIdx.x;
        int t = i >> 3, j = i & 7;
        sB[t][j] = xdbl[((size_t)(b * Ll + t0 + t)) * 80 + DTRANK + j];
    }
    __syncthreads();

    float An[8];
#pragma unroll
    for (int n = 0; n < 8; ++n) An[n] = -__expf(A_log[d * 8 + n]);

    float h[8], ap[8];
#pragma unroll
    for (int n = 0; n < 8; ++n) { h[n] = 0.0f; ap[n] = 1.0f; }

    const float* dptr = delta + ((size_t)(b * Ll + t0)) * DINNER + d;
    const unsigned short* xptr = xc + ((size_t)(b * Ll + t0)) * DINNER + d;

#pragma unroll 4
    for (int t = 0; t < CL; ++t) {
        float dl = dptr[(size_t)t * DINNER];
        float xv = bf2f(xptr[(size_t)t * DINNER]);
        float du = dl * xv;
#pragma unroll
        for (int n = 0; n < 8; ++n) {
            float dA = __expf(dl * An[n]);
            h[n] = fmaf(dA, h[n], du * sB[t][n]);
            ap[n] *= dA;
        }
    }

    size_t base = (((size_t)(b * NCH + c)) * 8) * DINNER + d;
#pragma unroll
    for (int n = 0; n < 8; ++n) {
        cs_a[base + (size_t)n * DINNER] = ap[n];
        cs_h[base + (size_t)n * DINNER] = h[n];
    }
}

// Pass 2: sequential combine; hin ALIASES cs_h (in-place) — read-before-write.
__global__ __launch_bounds__(256) void scan_pass2(
    const float* __restrict__ cs_a, const float* cs_h, float* hin)
{
    int idx = blockIdx.x * 256 + threadIdx.x;
    if (idx >= Bb * 8 * DINNER) return;
    int d = idx & (DINNER - 1);
    int n = (idx >> 11) & 7;
    int b = idx >> 14;
    float H = 0.0f;
#pragma unroll 4
    for (int c = 0; c < NCH; ++c) {
        size_t o = (((size_t)(b * NCH + c)) * 8 + n) * DINNER + d;
        float a = cs_a[o];
        float hh = cs_h[o];
        hin[o] = H;
        H = fmaf(a, H, hh);
    }
}

// Pass 3: replay with correct h_in; fused epilogue -> bf16 y. z dense bf16.
__global__ __launch_bounds__(256) void scan_pass3(
    const float* __restrict__ delta, const unsigned short* __restrict__ xc,
    const float* __restrict__ xdbl, const float* __restrict__ A_log,
    const float* __restrict__ hin, const unsigned short* __restrict__ z,
    const float* __restrict__ Dvec, unsigned short* __restrict__ y_bf)
{
    const int d = blockIdx.x * 256 + threadIdx.x;
    const int c = blockIdx.y;
    const int b = blockIdx.z;
    const int t0 = c * CL;

    __shared__ float sB[CL][8];
    __shared__ float sC[CL][8];
    {
        int i = threadIdx.x;
        int t = i >> 4, j = i & 15;
        float v = xdbl[((size_t)(b * Ll + t0 + t)) * 80 + DTRANK + j];
        if (j < 8) sB[t][j] = v; else sC[t][j - 8] = v;
        t = (i + 256) >> 4; j = (i + 256) & 15;
        v = xdbl[((size_t)(b * Ll + t0 + t)) * 80 + DTRANK + j];
        if (j < 8) sB[t][j] = v; else sC[t][j - 8] = v;
    }
    __syncthreads();

    float An[8];
#pragma unroll
    for (int n = 0; n < 8; ++n) An[n] = -__expf(A_log[d * 8 + n]);

    float h[8];
    size_t hbase = (((size_t)(b * NCH + c)) * 8) * DINNER + d;
#pragma unroll
    for (int n = 0; n < 8; ++n) h[n] = hin[hbase + (size_t)n * DINNER];

    const float Dd = Dvec[d];
    const float* dptr = delta + ((size_t)(b * Ll + t0)) * DINNER + d;
    const unsigned short* xptr = xc + ((size_t)(b * Ll + t0)) * DINNER + d;
    const unsigned short* zptr = z + ((size_t)(b * Ll + t0)) * DINNER + d;
    unsigned short* yptr = y_bf + ((size_t)(b * Ll + t0)) * DINNER + d;

    for (int t = 0; t < CL; ++t) {
        float dl = dptr[(size_t)t * DINNER];
        float xv = bf2f(xptr[(size_t)t * DINNER]);
        float du = dl * xv;
        float yt = 0.0f;
#pragma unroll
        for (int n = 0; n < 8; ++n) {
            float dA = __expf(dl * An[n]);
            h[n] = fmaf(dA, h[n], du * sB[t][n]);
            yt = fmaf(sC[t][n], h[n], yt);
        }
        float zv = bf2f(zptr[(size_t)t * DINNER]);
        yptr[(size_t)t * DINNER] = f2bf((yt + xv * Dd) * silu_f(zv));
    }
}

// ---------------------------------------------------------------------------
extern "C" void kernel_launch(void* const* d_in, const int* in_sizes, int n_in,
                              void* d_out, int out_size, void* d_ws, size_t ws_size,
                              hipStream_t stream)
{
    const float* x         = (const float*)d_in[0];
    const float* W_in      = (const float*)d_in[1];
    const float* dwk       = (const float*)d_in[2];
    const float* pwk       = (const float*)d_in[3];
    const float* conv_bias = (const float*)d_in[4];
    const float* W_x       = (const float*)d_in[5];
    const float* W_dt      = (const float*)d_in[6];
    const float* b_dt      = (const float*)d_in[7];
    const float* A_log     = (const float*)d_in[8];
    const float* Dv        = (const float*)d_in[9];
    const float* W_out     = (const float*)d_in[10];
    float* out = (float*)d_out;

    // workspace map (MiB offsets; peak 152.25 MiB <= proven 154)
    char* ws = (char*)d_ws;
    unsigned short* x_in_bf = (unsigned short*)(ws);                  // [0,16)   G1..conv
    unsigned short* z_bf    = (unsigned short*)(ws + (16ull << 20));  // [16,32)  G1..p3
    float*          delta   = (float*)(ws + (32ull << 20));           // [32,64)  G4..p3
    unsigned short* x_bf    = (unsigned short*)(ws + (64ull << 20));  // [64,72)  prep..G1
    unsigned short* y_bf    = (unsigned short*)(ws + (64ull << 20));  // [64,80)  p3..G5
    unsigned short* Wint    = (unsigned short*)(ws + (72ull << 20));  // [72,80)  prep..G1
    unsigned short* pw_t    = (unsigned short*)(ws + (80ull << 20));  // [80,88)  prep..G2
    unsigned short* xcp_bf  = (unsigned short*)(ws + (88ull << 20));  // [88,104) conv..G2
    unsigned short* xc_bf   = (unsigned short*)(ws + (104ull << 20)); // [104,120) G2..p3
    unsigned short* Woutt   = (unsigned short*)(ws + (120ull << 20)); // [120,124) prep..G5
    float*          xdbl    = (float*)(ws + (124ull << 20));          // [124,125.25) g3red..p3
    unsigned short* xdbl64  = (unsigned short*)(ws + (125ull << 20) + (512ull << 10)); // 0.5 MB
    float*          g3part  = (float*)(ws + (126ull << 20));          // [126,136) g3..g3red
    float*          cs_a    = (float*)(ws + (136ull << 20));          // [136,144) p1..p2
    float*          cs_h    = (float*)(ws + (144ull << 20));          // [144,152) p1..p3
    unsigned short* Wdtt    = (unsigned short*)(ws + (152ull << 20)); // 0.25 MB, prep..G4
    float*          hin     = cs_h;   // in-place
    dim3 blk(256);

    // prep: cast + 4 transposes fused into one dispatch
    prep_all<<<14464, blk, 0, stream>>>(x, W_in, pwk, W_out, W_dt,
                                        x_bf, Wint, pw_t, Woutt, Wdtt);

    // G1: xz = x @ W_in, deinterleaved bf16 (x_in | z). 256^2-tile
    // deep-pipeline kernel (HW-verified r3/r6), grid 16x16 = 1/CU.
    gemm256_g1<<<dim3((2 * DINNER) / 256, MM / 256), dim3(512), 0, stream>>>(
        x_bf, Wint, x_in_bf, z_bf,
        /*K*/DMODEL, /*lda*/DMODEL, /*ldb*/DMODEL, /*ldc*/DINNER,
        /*nsplit*/DINNER);

    // depthwise causal conv (bf16 in, bf16 out)
    dwconv_kernel<<<MM * DINNER / 4 / 256, blk, 0, stream>>>(x_in_bf, dwk, xcp_bf);

    // G2: xc = silu(conv @ pw + conv_bias) -> bf16. r6 2-phase version
    // RESTORED (HW-verified 49.4us; r7's 3-buffer variant regressed).
    gemm256x128<1, unsigned short>
        <<<dim3(DINNER / 128, MM / 256), dim3(512), 0, stream>>>(
        xcp_bf, pw_t, xc_bf,
        /*K*/DINNER, /*lda*/DINNER, /*ldb*/DINNER, /*ldc*/DINNER, conv_bias);

    // G3: x_dbl partials = xc @ W_x (split-K fp32) + materialized reduce
    g3_splitk<<<dim3(MM / 64, G3_KCH), blk, 0, stream>>>(xc_bf, W_x, g3part);
    g3_reduce<<<(MM * 80 / 4 + 255) / 256, blk, 0, stream>>>(g3part, xdbl, xdbl64);

    // G4: delta = softplus(xdbl64 @ Wdtt^T + b_dt) — MFMA, K=64. r8: TN=64,
    // grid 32x32 = 1024 blocks = 4/CU (was TN=128, 2/CU; r7 profile showed
    // memory-bound, MfmaUtil 0.4% — more blocks overlap the store bursts).
    // No XCD swizzle: inputs are 1.3 MB, L2-resident.
    mfma_gemm<2, 4, 64, float>
        <<<dim3(DINNER / 64, MM / 128), blk, 0, stream>>>(
        xdbl64, Wdtt, delta, delta, DINNER + 1,
        MM, DINNER, DTRANK, DTRANK, DTRANK, DINNER, b_dt);

    // selective scan, 3-pass chunked (CL=32, NCH=64 — proven)
    scan_pass1<<<dim3(DINNER / 256, NCH, Bb), blk, 0, stream>>>(
        delta, xc_bf, xdbl, A_log, cs_a, cs_h);
    scan_pass2<<<(Bb * 8 * DINNER + 255) / 256, blk, 0, stream>>>(cs_a, cs_h, hin);
    scan_pass3<<<dim3(DINNER / 256, NCH, Bb), blk, 0, stream>>>(
        delta, xc_bf, xdbl, A_log, hin, z_bf, Dv, y_bf);

    // G5: out = y @ W_out. NW=4, TN=64 -> 512 blocks, direct write,
    // + XCD region swizzle.
    mfma_gemm<0, 4, 64, float, 8, 8>
        <<<dim3(DMODEL / 64, MM / 128), blk, 0, stream>>>(
        y_bf, Woutt, out, out, DMODEL + 1,
        MM, DMODEL, DINNER, DINNER, DINNER, DMODEL, nullptr);
}

// Round 9
// 359.603 us; speedup vs baseline: 1.1408x; 1.0022x over previous
//
#include <hip/hip_runtime.h>
#include <math.h>

// Problem constants
#define Bb 2
#define Ll 2048
#define DMODEL 1024
#define DINNER 2048
#define DSTATE 8
#define DTRANK 64
#define DCONV 4
#define MM (Bb*Ll)          // 4096 rows
// scan chunking (CL=32 proven best)
#define NCH 64
#define CL 32               // NCH*CL == Ll
// G3 split-K
#define G3_KCH 8
#define G3_KC (DINNER / G3_KCH)   // 256

typedef __attribute__((ext_vector_type(8))) short    bf16x8;
typedef __attribute__((ext_vector_type(4))) float    f32x4;

__device__ __forceinline__ float silu_f(float x) {
    return x / (1.0f + __expf(-x));
}
__device__ __forceinline__ float softplus_f(float x) {
    return fmaxf(x, 0.0f) + log1pf(__expf(-fabsf(x)));
}
__device__ __forceinline__ unsigned short f2bf(float f) {
    unsigned int u = __float_as_uint(f);
    u += 0x7fffu + ((u >> 16) & 1u);      // RNE
    return (unsigned short)(u >> 16);
}
__device__ __forceinline__ float bf2f(unsigned short u) {
    return __uint_as_float(((unsigned int)u) << 16);
}
// async 16B global->LDS (wave-uniform LDS base + lane*16 dest)
__device__ __forceinline__ void async_cp16(const unsigned short* g, unsigned short* l) {
    __builtin_amdgcn_global_load_lds(
        (const __attribute__((address_space(1))) void*)g,
        (__attribute__((address_space(3))) void*)l, 16, 0, 0);
}

// ---------------------------------------------------------------------------
// bf16 MFMA GEMM (r11-proven): NW waves, tile 128 x TN, BK=32, double-
// buffered async staging, flat LDS + 16B-slot XOR swizzle -> 0 bank
// conflicts. Used for G4 (TN=64, 4/CU — r8-verified, anomaly gone) and G5.
// EPI: 0 none, 1 silu(x+bias[n]), 2 softplus(x+bias[n]).
// RX/RY XCD region swizzle; requires (gridDim.x/RX)*(gridDim.y/RY) == 8.
// ---------------------------------------------------------------------------
template <int EPI, int NW, int TN, typename OT, int RX = 0, int RY = 1>
__global__ __launch_bounds__(NW * 64, 4) void mfma_gemm(
    const unsigned short* __restrict__ A, const unsigned short* __restrict__ Bt,
    OT* __restrict__ C, OT* __restrict__ C2, int nsplit,
    int M, int N, int K, int lda, int ldb, int ldc,
    const float* __restrict__ bias)
{
    constexpr int NT   = NW * 64;     // threads
    constexpr int WNC  = NW / 2;      // waves along n
    constexpr int WNE  = TN / WNC;    // wave n-extent
    constexpr int NJ   = WNE / 16;    // b-frags per wave
    constexpr int RPP  = NT / 4;      // tile rows staged per pass
    constexpr int APASS = 128 / RPP;
    constexpr int BPASS = TN / RPP;

    __shared__ unsigned short As[2][128 * 32];
    __shared__ unsigned short Bs[2][TN * 32];

    int bxx = blockIdx.x, byy = blockIdx.y;
    if constexpr (RX > 0) {
        const int f = blockIdx.y * gridDim.x + blockIdx.x;
        const int c = f & 7, q = f >> 3;
        const int rgw = gridDim.x / RX;
        bxx = (c % rgw) * RX + (q % RX);
        byy = (c / rgw) * RY + (q / RX);
    }
    const int bm = byy * 128;
    const int bn = bxx * TN;
    const int tid  = threadIdx.x;
    const int w    = tid >> 6;
    const int lane = tid & 63;
    const int wm = (w / WNC) * 64;
    const int wn = (w % WNC) * WNE;
    const int lr = lane & 15;
    const int lq = lane >> 4;

    const int row  = tid >> 2;
    const int sp   = tid & 3;
    const int slog = sp ^ ((row >> 1) & 3);
    const unsigned short* gA = A  + (size_t)(bm + row) * lda + slog * 8;
    const unsigned short* gB = Bt + (size_t)(bn + row) * ldb + slog * 8;
    const int st = tid * 8;

    const int fsw = (lq ^ ((lr >> 1) & 3)) * 8;

    f32x4 acc[4][NJ];
#pragma unroll
    for (int i = 0; i < 4; ++i)
#pragma unroll
        for (int j = 0; j < NJ; ++j) acc[i][j] = (f32x4){0.f, 0.f, 0.f, 0.f};

#pragma unroll
    for (int p = 0; p < APASS; ++p)
        async_cp16(gA + (size_t)p * RPP * lda, &As[0][p * RPP * 32 + st]);
#pragma unroll
    for (int p = 0; p < BPASS; ++p)
        async_cp16(gB + (size_t)p * RPP * ldb, &Bs[0][p * RPP * 32 + st]);

    int cur = 0;
    for (int k0 = 0; k0 < K; k0 += 32, cur ^= 1) {
        __syncthreads();
        const int nk = k0 + 32;
        if (nk < K) {
            const int nb = cur ^ 1;
#pragma unroll
            for (int p = 0; p < APASS; ++p)
                async_cp16(gA + (size_t)p * RPP * lda + nk, &As[nb][p * RPP * 32 + st]);
#pragma unroll
            for (int p = 0; p < BPASS; ++p)
                async_cp16(gB + (size_t)p * RPP * ldb + nk, &Bs[nb][p * RPP * 32 + st]);
        }

        bf16x8 a[4], b[NJ];
#pragma unroll
        for (int i = 0; i < 4; ++i)
            a[i] = *(const bf16x8*)&As[cur][(wm + i * 16 + lr) * 32 + fsw];
#pragma unroll
        for (int j = 0; j < NJ; ++j)
            b[j] = *(const bf16x8*)&Bs[cur][(wn + j * 16 + lr) * 32 + fsw];
#pragma unroll
        for (int i = 0; i < 4; ++i)
#pragma unroll
            for (int j = 0; j < NJ; ++j)
                acc[i][j] = __builtin_amdgcn_mfma_f32_16x16x32_bf16(
                    a[i], b[j], acc[i][j], 0, 0, 0);
    }

#pragma unroll
    for (int i = 0; i < 4; ++i) {
        const int row0 = bm + wm + i * 16 + lq * 4;
#pragma unroll
        for (int j = 0; j < NJ; ++j) {
            const int col = bn + wn + j * 16 + lr;
            OT* Cb; int colb;
            if (col < nsplit) { Cb = C; colb = col; }
            else              { Cb = C2; colb = col - nsplit; }
            float bv = (EPI != 0) ? bias[col] : 0.0f;
#pragma unroll
            for (int r = 0; r < 4; ++r) {
                float v = acc[i][j][r];
                if (EPI == 1) v = silu_f(v + bv);
                if (EPI == 2) v = softplus_f(v + bv);
                if (sizeof(OT) == 2)
                    Cb[(size_t)(row0 + r) * ldc + colb] = (OT)f2bf(v);
                else
                    Cb[(size_t)(row0 + r) * ldc + colb] = (OT)v;
            }
        }
    }
}

// ---------------------------------------------------------------------------
// 256x256-tile deep-pipeline bf16 GEMM (G1). HW-VERIFIED r3/r6/r8 (passed).
// Counted-vmcnt 4-phase schedule; FIFO trace in r1/r2 history. UNCHANGED.
// ---------------------------------------------------------------------------
template <bool I1, bool I2, int VMA, int VMB>
__device__ __forceinline__ void g1_tile(
    int kt, const unsigned short* __restrict__ gA,
    const unsigned short* __restrict__ gB, int lda, int ldb,
    unsigned short* As, unsigned short* Bs, int st,
    int wm, int wn, int lr, int fsw, f32x4 (&acc)[8][4])
{
    const int cur = kt & 1;
    const int sb0 = (cur << 1) * 8192;
    const int sb1 = ((cur << 1) | 1) * 8192;
    const int nb1 = ((kt + 1) & 1) << 1;
    const int nb2 = ((kt + 2) & 1) << 1;
    bf16x8 a[4], b[4];

    // ---- phase 0: kh=0, mh=0 ----
#pragma unroll
    for (int i = 0; i < 4; ++i)
        a[i] = *(const bf16x8*)&As[sb0 + (wm + i * 16 + lr) * 32 + fsw];
#pragma unroll
    for (int j = 0; j < 4; ++j)
        b[j] = *(const bf16x8*)&Bs[sb0 + (wn + j * 16 + lr) * 32 + fsw];
    if (I1) {
        const unsigned short* s = gA + (kt + 1) * 64 + 32;
        unsigned short* d = &As[(nb1 | 1) * 8192 + st];
        async_cp16(s, d);
        async_cp16(s + (size_t)128 * lda, d + 4096);
        __builtin_amdgcn_sched_barrier(0);
    }
    __builtin_amdgcn_s_barrier();
    asm volatile("s_waitcnt lgkmcnt(0)" ::: "memory");
    __builtin_amdgcn_sched_barrier(0);
    __builtin_amdgcn_s_setprio(1);
#pragma unroll
    for (int i = 0; i < 4; ++i)
#pragma unroll
        for (int j = 0; j < 4; ++j)
            acc[i][j] = __builtin_amdgcn_mfma_f32_16x16x32_bf16(
                a[i], b[j], acc[i][j], 0, 0, 0);
    __builtin_amdgcn_s_setprio(0);
    __builtin_amdgcn_s_barrier();

    // ---- phase 1: kh=0, mh=1 ----
#pragma unroll
    for (int i = 0; i < 4; ++i)
        a[i] = *(const bf16x8*)&As[sb0 + (wm + (4 + i) * 16 + lr) * 32 + fsw];
    if (I1) {
        const unsigned short* s = gB + (kt + 1) * 64 + 32;
        unsigned short* d = &Bs[(nb1 | 1) * 8192 + st];
        async_cp16(s, d);
        async_cp16(s + (size_t)128 * ldb, d + 4096);
        __builtin_amdgcn_sched_barrier(0);
    }
    __builtin_amdgcn_s_barrier();
    asm volatile("s_waitcnt lgkmcnt(0)" ::: "memory");
    __builtin_amdgcn_sched_barrier(0);
    __builtin_amdgcn_s_setprio(1);
#pragma unroll
    for (int i = 0; i < 4; ++i)
#pragma unroll
        for (int j = 0; j < 4; ++j)
            acc[4 + i][j] = __builtin_amdgcn_mfma_f32_16x16x32_bf16(
                a[i], b[j], acc[4 + i][j], 0, 0, 0);
    __builtin_amdgcn_s_setprio(0);
    asm volatile("s_waitcnt vmcnt(%0)" :: "n"(VMA) : "memory");
    __builtin_amdgcn_s_barrier();

    // ---- phase 2: kh=1, mh=0 ----
#pragma unroll
    for (int i = 0; i < 4; ++i)
        a[i] = *(const bf16x8*)&As[sb1 + (wm + i * 16 + lr) * 32 + fsw];
#pragma unroll
    for (int j = 0; j < 4; ++j)
        b[j] = *(const bf16x8*)&Bs[sb1 + (wn + j * 16 + lr) * 32 + fsw];
    if (I2) {
        const unsigned short* s = gA + (kt + 2) * 64;
        unsigned short* d = &As[nb2 * 8192 + st];
        async_cp16(s, d);
        async_cp16(s + (size_t)128 * lda, d + 4096);
        __builtin_amdgcn_sched_barrier(0);
    }
    __builtin_amdgcn_s_barrier();
    asm volatile("s_waitcnt lgkmcnt(0)" ::: "memory");
    __builtin_amdgcn_sched_barrier(0);
    __builtin_amdgcn_s_setprio(1);
#pragma unroll
    for (int i = 0; i < 4; ++i)
#pragma unroll
        for (int j = 0; j < 4; ++j)
            acc[i][j] = __builtin_amdgcn_mfma_f32_16x16x32_bf16(
                a[i], b[j], acc[i][j], 0, 0, 0);
    __builtin_amdgcn_s_setprio(0);
    __builtin_amdgcn_s_barrier();

    // ---- phase 3: kh=1, mh=1 ----
#pragma unroll
    for (int i = 0; i < 4; ++i)
        a[i] = *(const bf16x8*)&As[sb1 + (wm + (4 + i) * 16 + lr) * 32 + fsw];
    if (I2) {
        const unsigned short* s = gB + (kt + 2) * 64;
        unsigned short* d = &Bs[nb2 * 8192 + st];
        async_cp16(s, d);
        async_cp16(s + (size_t)128 * ldb, d + 4096);
        __builtin_amdgcn_sched_barrier(0);
    }
    __builtin_amdgcn_s_barrier();
    asm volatile("s_waitcnt lgkmcnt(0)" ::: "memory");
    __builtin_amdgcn_sched_barrier(0);
    __builtin_amdgcn_s_setprio(1);
#pragma unroll
    for (int i = 0; i < 4; ++i)
#pragma unroll
        for (int j = 0; j < 4; ++j)
            acc[4 + i][j] = __builtin_amdgcn_mfma_f32_16x16x32_bf16(
                a[i], b[j], acc[4 + i][j], 0, 0, 0);
    __builtin_amdgcn_s_setprio(0);
    asm volatile("s_waitcnt vmcnt(%0)" :: "n"(VMB) : "memory");
    __builtin_amdgcn_s_barrier();
}

__global__ __launch_bounds__(512, 2) void gemm256_g1(
    const unsigned short* __restrict__ A, const unsigned short* __restrict__ Bt,
    unsigned short* __restrict__ Cx, unsigned short* __restrict__ Cz,
    int K, int lda, int ldb, int ldc, int nsplit)
{
    __shared__ unsigned short As[4 * 8192];   // 64 KB
    __shared__ unsigned short Bs[4 * 8192];   // 64 KB

    int bx, by;
    {
        const int f = blockIdx.y * gridDim.x + blockIdx.x;
        const int c = f & 7, q = f >> 3;
        const int rgw = gridDim.x >> 3;
        bx = (c % rgw) * 8 + (q & 7);
        by = (c / rgw) * 4 + (q >> 3);
    }
    const int bm = by * 256, bn = bx * 256;
    const int tid  = threadIdx.x;
    const int lane = tid & 63;
    const int w    = tid >> 6;
    const int wm = (w >> 2) << 7;
    const int wn = (w & 3) << 6;
    const int lr = lane & 15;
    const int lq = lane >> 4;
    const int fsw = (lq ^ ((lr >> 1) & 3)) * 8;

    const int row  = tid >> 2;
    const int slog = (tid & 3) ^ ((row >> 1) & 3);
    const unsigned short* gA = A  + (size_t)(bm + row) * lda + slog * 8;
    const unsigned short* gB = Bt + (size_t)(bn + row) * ldb + slog * 8;
    const int st = tid * 8;
    const int NT = K >> 6;

    f32x4 acc[8][4];
#pragma unroll
    for (int i = 0; i < 8; ++i)
#pragma unroll
        for (int j = 0; j < 4; ++j) acc[i][j] = (f32x4){0.f, 0.f, 0.f, 0.f};

    auto stg = [&](const unsigned short* g, int ld, unsigned short* d) {
        async_cp16(g, d);
        async_cp16(g + (size_t)128 * ld, d + 4096);
    };
    stg(gA,      lda, As + 0 * 8192 + st);
    __builtin_amdgcn_sched_barrier(0);
    stg(gB,      ldb, Bs + 0 * 8192 + st);
    __builtin_amdgcn_sched_barrier(0);
    stg(gA + 32, lda, As + 1 * 8192 + st);
    __builtin_amdgcn_sched_barrier(0);
    stg(gB + 32, ldb, Bs + 1 * 8192 + st);
    __builtin_amdgcn_sched_barrier(0);
    stg(gA + 64, lda, As + 2 * 8192 + st);
    __builtin_amdgcn_sched_barrier(0);
    stg(gB + 64, ldb, Bs + 2 * 8192 + st);
    asm volatile("s_waitcnt vmcnt(8)" ::: "memory");
    __builtin_amdgcn_sched_barrier(0);
    __builtin_amdgcn_s_barrier();

    for (int kt = 0; kt + 2 < NT; ++kt)
        g1_tile<true, true, 8, 8>(kt, gA, gB, lda, ldb,
                                  As, Bs, st, wm, wn, lr, fsw, acc);
    g1_tile<true,  false, 8, 4>(NT - 2, gA, gB, lda, ldb,
                                As, Bs, st, wm, wn, lr, fsw, acc);
    g1_tile<false, false, 0, 0>(NT - 1, gA, gB, lda, ldb,
                                As, Bs, st, wm, wn, lr, fsw, acc);

#pragma unroll
    for (int i = 0; i < 8; ++i) {
        const int row0 = bm + wm + i * 16 + lq * 4;
#pragma unroll
        for (int j = 0; j < 4; ++j) {
            const int col = bn + wn + j * 16 + lr;
            unsigned short* Cb; int colb;
            if (col < nsplit) { Cb = Cx; colb = col; }
            else              { Cb = Cz; colb = col - nsplit; }
#pragma unroll
            for (int r = 0; r < 4; ++r)
                Cb[(size_t)(row0 + r) * ldc + colb] = f2bf(acc[i][j][r]);
        }
    }
}

// ---------------------------------------------------------------------------
// NEW r9: G2 as 128x128-tile, 4-wave (2Mx2N), counted-vmcnt 2-phase — the
// r6/r8-proven g2_tile control flow with geometry shrunk so LDS = 64 KB ->
// 2 BLOCKS/CU (r8 G2 ran 1 block/CU, OccupancyPercent 18%, MfmaUtil 28%:
// when its 8 lockstep waves hit the phase-end vmcnt the whole CU idled).
// Two independent barrier domains per CU restore cross-block MFMA||stage
// overlap (m114) while keeping the counted-vmcnt pipeline.
// Geometry: per kh-slot A = B = 128x32 = 8 KB; 4 slots each (2 bufs x 2 kh)
// = 32+32 KB. Stage group = 4 cp16 (A rows r,r+64; B rows r,r+64),
// r = tid>>2, slot = tid&3, st = tid*8 (+2048 shorts for +64 rows).
// Swizzle invariant: ((row+64)>>1)&3 == (row>>1)&3 (64 even multiple of 4).
// FIFO (4 instr/group; G_{2t}=kh0(t), G_{2t+1}=kh1(t); G_n = instrs
// 4n+1..4n+4): prologue G0,G1,G2 = 12 instrs, vmcnt(8) -> G0 done.
// Tile kt: ph0 issues G_{2kt+3}; end-ph0 issued = 8kt+16, ph1 needs
// G_{2kt+1} (ends 8kt+8) -> vmcnt(8). ph1 issues G_{2kt+4}; end-ph1
// issued = 8kt+20, next needs G_{2kt+2} (ends 8kt+12) -> vmcnt(8).
// Tails: NT-2 <true,false,8,4>; NT-1 <false,false,0,0>. (NT=32 trace:
// end-ph0(30) issued 256, G61 ends 248 -> 8 ok; end-ph1(30) G62 ends
// 252 -> 4 ok; ph0(31) vmcnt(0) drains G63.)
// WAR: identical to g2_tile — staged slot's last readers drained by that
// phase's own lgkmcnt(0) + end-barrier; stage issue is after that barrier.
// Requires K mult 64, NT>=3, M,N mult 128.
// ---------------------------------------------------------------------------
template <bool I1, bool I2, int VMA, int VMB>
__device__ __forceinline__ void g2c_tile(
    int kt, const unsigned short* __restrict__ gA,
    const unsigned short* __restrict__ gB, int lda, int ldb,
    unsigned short* As, unsigned short* Bs, int st,
    int wm, int wn, int lr, int fsw, f32x4 (&acc)[4][4])
{
    const int cur = kt & 1;
    const int sa0 = (cur << 1) * 4096;          // A slot: buf cur, kh0 (shorts)
    const int sa1 = ((cur << 1) | 1) * 4096;
    const int sb0 = (cur << 1) * 4096;          // B slot: buf cur, kh0
    const int sb1 = ((cur << 1) | 1) * 4096;
    const int nb1 = (((kt + 1) & 1) << 1) | 1;  // slot idx for kh1(kt+1)
    const int nb2 = ((kt + 2) & 1) << 1;        // slot idx for kh0(kt+2)
    bf16x8 a[4], b[4];

    // ---- phase 0: kh=0 ----
#pragma unroll
    for (int i = 0; i < 4; ++i)
        a[i] = *(const bf16x8*)&As[sa0 + (wm + i * 16 + lr) * 32 + fsw];
#pragma unroll
    for (int j = 0; j < 4; ++j)
        b[j] = *(const bf16x8*)&Bs[sb0 + (wn + j * 16 + lr) * 32 + fsw];
    if (I1) {   // stage kh1(kt+1): A(2) + B(2)
        const unsigned short* sA = gA + (kt + 1) * 64 + 32;
        unsigned short* dA = &As[nb1 * 4096 + st];
        async_cp16(sA, dA);
        async_cp16(sA + (size_t)64 * lda, dA + 2048);
        const unsigned short* sB = gB + (kt + 1) * 64 + 32;
        unsigned short* dB = &Bs[nb1 * 4096 + st];
        async_cp16(sB, dB);
        async_cp16(sB + (size_t)64 * ldb, dB + 2048);
        __builtin_amdgcn_sched_barrier(0);
    }
    __builtin_amdgcn_s_barrier();
    asm volatile("s_waitcnt lgkmcnt(0)" ::: "memory");
    __builtin_amdgcn_sched_barrier(0);
    __builtin_amdgcn_s_setprio(1);
#pragma unroll
    for (int i = 0; i < 4; ++i)
#pragma unroll
        for (int j = 0; j < 4; ++j)
            acc[i][j] = __builtin_amdgcn_mfma_f32_16x16x32_bf16(
                a[i], b[j], acc[i][j], 0, 0, 0);
    __builtin_amdgcn_s_setprio(0);
    asm volatile("s_waitcnt vmcnt(%0)" :: "n"(VMA) : "memory");
    __builtin_amdgcn_s_barrier();

    // ---- phase 1: kh=1 ----
#pragma unroll
    for (int i = 0; i < 4; ++i)
        a[i] = *(const bf16x8*)&As[sa1 + (wm + i * 16 + lr) * 32 + fsw];
#pragma unroll
    for (int j = 0; j < 4; ++j)
        b[j] = *(const bf16x8*)&Bs[sb1 + (wn + j * 16 + lr) * 32 + fsw];
    if (I2) {   // stage kh0(kt+2): A(2) + B(2)
        const unsigned short* sA = gA + (kt + 2) * 64;
        unsigned short* dA = &As[nb2 * 4096 + st];
        async_cp16(sA, dA);
        async_cp16(sA + (size_t)64 * lda, dA + 2048);
        const unsigned short* sB = gB + (kt + 2) * 64;
        unsigned short* dB = &Bs[nb2 * 4096 + st];
        async_cp16(sB, dB);
        async_cp16(sB + (size_t)64 * ldb, dB + 2048);
        __builtin_amdgcn_sched_barrier(0);
    }
    __builtin_amdgcn_s_barrier();
    asm volatile("s_waitcnt lgkmcnt(0)" ::: "memory");
    __builtin_amdgcn_sched_barrier(0);
    __builtin_amdgcn_s_setprio(1);
#pragma unroll
    for (int i = 0; i < 4; ++i)
#pragma unroll
        for (int j = 0; j < 4; ++j)
            acc[i][j] = __builtin_amdgcn_mfma_f32_16x16x32_bf16(
                a[i], b[j], acc[i][j], 0, 0, 0);
    __builtin_amdgcn_s_setprio(0);
    asm volatile("s_waitcnt vmcnt(%0)" :: "n"(VMB) : "memory");
    __builtin_amdgcn_s_barrier();
}

template <int EPI, typename OT>
__global__ __launch_bounds__(256, 2) void gemm128x128(
    const unsigned short* __restrict__ A, const unsigned short* __restrict__ Bt,
    OT* __restrict__ C, int K, int lda, int ldb, int ldc,
    const float* __restrict__ bias)
{
    __shared__ unsigned short As[4 * 4096];   // 4 kh-slots x 8 KB = 32 KB
    __shared__ unsigned short Bs[4 * 4096];   // 32 KB  -> total 64 KB, 2/CU

    // XCD region swizzle (grid 16x32): 8 regions of 8x8
    int bx, by;
    {
        const int f = blockIdx.y * gridDim.x + blockIdx.x;
        const int c = f & 7, q = f >> 3;
        const int rgw = gridDim.x >> 3;       // = 2
        bx = (c % rgw) * 8 + (q & 7);
        by = (c / rgw) * 8 + (q >> 3);
    }
    const int bm = by * 128, bn = bx * 128;
    const int tid  = threadIdx.x;
    const int lane = tid & 63;
    const int w    = tid >> 6;                // 0..3
    const int wm = (w >> 1) << 6;             // 0,64
    const int wn = (w & 1) << 6;              // 0,64
    const int lr = lane & 15;
    const int lq = lane >> 4;
    const int fsw = (lq ^ ((lr >> 1) & 3)) * 8;

    // staging: thread t -> row t>>2 (+64 on 2nd instr), 16B slot t&3
    const int row  = tid >> 2;                // 0..63
    const int slog = (tid & 3) ^ ((row >> 1) & 3);
    const unsigned short* gA = A  + (size_t)(bm + row) * lda + slog * 8;
    const unsigned short* gB = Bt + (size_t)(bn + row) * ldb + slog * 8;
    const int st = tid * 8;                   // shorts, [0,2048)
    const int NT = K >> 6;                    // requires >= 3

    f32x4 acc[4][4];
#pragma unroll
    for (int i = 0; i < 4; ++i)
#pragma unroll
        for (int j = 0; j < 4; ++j) acc[i][j] = (f32x4){0.f, 0.f, 0.f, 0.f};

    // prologue: kh0(0)->slot0, kh1(0)->slot1, kh0(1)->slot2; order pinned
    auto stg = [&](int ko, int slot) {
        const unsigned short* sA = gA + ko;
        unsigned short* dA = &As[slot * 4096 + st];
        async_cp16(sA, dA);
        async_cp16(sA + (size_t)64 * lda, dA + 2048);
        const unsigned short* sB = gB + ko;
        unsigned short* dB = &Bs[slot * 4096 + st];
        async_cp16(sB, dB);
        async_cp16(sB + (size_t)64 * ldb, dB + 2048);
    };
    stg(0, 0);
    __builtin_amdgcn_sched_barrier(0);
    stg(32, 1);
    __builtin_amdgcn_sched_barrier(0);
    stg(64, 2);
    asm volatile("s_waitcnt vmcnt(8)" ::: "memory");   // kh0(0) landed
    __builtin_amdgcn_sched_barrier(0);
    __builtin_amdgcn_s_barrier();

    for (int kt = 0; kt + 2 < NT; ++kt)
        g2c_tile<true, true, 8, 8>(kt, gA, gB, lda, ldb,
                                   As, Bs, st, wm, wn, lr, fsw, acc);
    g2c_tile<true,  false, 8, 4>(NT - 2, gA, gB, lda, ldb,
                                 As, Bs, st, wm, wn, lr, fsw, acc);
    g2c_tile<false, false, 0, 0>(NT - 1, gA, gB, lda, ldb,
                                 As, Bs, st, wm, wn, lr, fsw, acc);

    // epilogue: C/D layout col = lane&15, row = (lane>>4)*4 + reg
#pragma unroll
    for (int i = 0; i < 4; ++i) {
        const int row0 = bm + wm + i * 16 + lq * 4;
#pragma unroll
        for (int j = 0; j < 4; ++j) {
            const int col = bn + wn + j * 16 + lr;
            float bv = (EPI != 0) ? bias[col] : 0.0f;
#pragma unroll
            for (int r = 0; r < 4; ++r) {
                float v = acc[i][j][r];
                if (EPI == 1) v = silu_f(v + bv);
                if (EPI == 2) v = softplus_f(v + bv);
                if (sizeof(OT) == 2)
                    C[(size_t)(row0 + r) * ldc + col] = (OT)f2bf(v);
                else
                    C[(size_t)(row0 + r) * ldc + col] = (OT)v;
            }
        }
    }
}

// ---------------------------------------------------------------------------
// prep_all: ONE kernel for input cast + 4 weight transpose-casts.
// ---------------------------------------------------------------------------
__global__ __launch_bounds__(256) void prep_all(
    const float* __restrict__ x, const float* __restrict__ W_in,
    const float* __restrict__ pwk, const float* __restrict__ W_out,
    const float* __restrict__ W_dt,
    unsigned short* __restrict__ x_bf, unsigned short* __restrict__ Wint,
    unsigned short* __restrict__ pw_t, unsigned short* __restrict__ Woutt,
    unsigned short* __restrict__ Wdtt)
{
    const int b = blockIdx.x;
    const int t = threadIdx.x;
    if (b < 4096) {                       // cast
        int i = b * 1024 + t * 4;
        float4 v = *(const float4*)&x[i];
        ushort4 o;
        o.x = f2bf(v.x); o.y = f2bf(v.y); o.z = f2bf(v.z); o.w = f2bf(v.w);
        *(ushort4*)&x_bf[i] = o;
        return;
    }
    const float* src; unsigned short* dst; int R, C, c0, r0;
    if (b < 8192) {
        int bi = b - 4096; src = W_in; dst = Wint; R = 1024; C = 4096;
        c0 = (bi & 127) * 32; r0 = (bi >> 7) * 32;
    } else if (b < 12288) {
        int bi = b - 8192; src = pwk; dst = pw_t; R = 2048; C = 2048;
        c0 = (bi & 63) * 32; r0 = (bi >> 6) * 32;
    } else if (b < 14336) {
        int bi = b - 12288; src = W_out; dst = Woutt; R = 2048; C = 1024;
        c0 = (bi & 31) * 32; r0 = (bi >> 5) * 32;
    } else {
        int bi = b - 14336; src = W_dt; dst = Wdtt; R = 64; C = 2048;
        c0 = (bi & 63) * 32; r0 = (bi >> 6) * 32;
    }
    __shared__ float tile[32][33];
    const int tx = t & 31;
    const int ty = t >> 5;
#pragma unroll
    for (int i = 0; i < 32; i += 8)
        tile[ty + i][tx] = src[(size_t)(r0 + ty + i) * C + c0 + tx];
    __syncthreads();
#pragma unroll
    for (int i = 0; i < 32; i += 8)
        dst[(size_t)(c0 + ty + i) * R + r0 + tx] = f2bf(tile[tx][ty + i]);
}

// ---------------------------------------------------------------------------
// G3 split-K: part[kc][M][80] = xc_bf[:, kc*256:(kc+1)*256] @ W_x-chunk
// ---------------------------------------------------------------------------
__global__ __launch_bounds__(256) void g3_splitk(
    const unsigned short* __restrict__ xc, const float* __restrict__ Wx,
    float* __restrict__ part)
{
    __shared__ float As[16][68];
    __shared__ float Bs[16][85];
    const int m0 = blockIdx.x * 64;
    const int kb = blockIdx.y * G3_KC;
    const int t = threadIdx.x;
    const int tr = t >> 4;
    const int tc = t & 15;

    const int arow = t >> 2;
    const int ak4  = (t & 3) * 4;
    const int bk   = t >> 4;
    const int bc   = (t & 15) * 5;

    float acc[4][5];
#pragma unroll
    for (int r = 0; r < 4; ++r)
#pragma unroll
        for (int c = 0; c < 5; ++c) acc[r][c] = 0.0f;

    for (int k0 = 0; k0 < G3_KC; k0 += 16) {
        ushort4 av = *(const ushort4*)&xc[(size_t)(m0 + arow) * DINNER + kb + k0 + ak4];
        float bv[5];
#pragma unroll
        for (int q = 0; q < 5; ++q)
            bv[q] = Wx[(size_t)(kb + k0 + bk) * 80 + bc + q];
        __syncthreads();
        As[ak4 + 0][arow] = bf2f(av.x);
        As[ak4 + 1][arow] = bf2f(av.y);
        As[ak4 + 2][arow] = bf2f(av.z);
        As[ak4 + 3][arow] = bf2f(av.w);
#pragma unroll
        for (int q = 0; q < 5; ++q) Bs[bk][bc + q] = bv[q];
        __syncthreads();
#pragma unroll
        for (int k = 0; k < 16; ++k) {
            float a[4], b[5];
#pragma unroll
            for (int r = 0; r < 4; ++r) a[r] = As[k][tr * 4 + r];
#pragma unroll
            for (int c = 0; c < 5; ++c) b[c] = Bs[k][tc * 5 + c];
#pragma unroll
            for (int r = 0; r < 4; ++r)
#pragma unroll
                for (int c = 0; c < 5; ++c)
                    acc[r][c] = fmaf(a[r], b[c], acc[r][c]);
        }
    }
#pragma unroll
    for (int r = 0; r < 4; ++r)
#pragma unroll
        for (int c = 0; c < 5; ++c)
            part[((size_t)blockIdx.y * MM + m0 + tr * 4 + r) * 80 + tc * 5 + c] = acc[r][c];
}

// reduce 8 partials -> xdbl fp32 AND bf16 delta cols [M][64] for G4.
__global__ __launch_bounds__(256) void g3_reduce(
    const float* __restrict__ part, float* __restrict__ xdbl,
    unsigned short* __restrict__ xdbl64)
{
    int i = (blockIdx.x * 256 + threadIdx.x) * 4;
    if (i >= MM * 80) return;
    float4 s = *(const float4*)&part[i];
#pragma unroll
    for (int c = 1; c < G3_KCH; ++c) {
        float4 p = *(const float4*)&part[(size_t)c * MM * 80 + i];
        s.x += p.x; s.y += p.y; s.z += p.z; s.w += p.w;
    }
    *(float4*)&xdbl[i] = s;
    int col = i % 80;
    if (col < 64) {
        int row = i / 80;
        ushort4 o;
        o.x = f2bf(s.x); o.y = f2bf(s.y); o.z = f2bf(s.z); o.w = f2bf(s.w);
        *(ushort4*)&xdbl64[(size_t)row * 64 + col] = o;
    }
}

// ---------------------------------------------------------------------------
// Depthwise causal conv on dense bf16 x_in [M][DINNER]; bf16 out; x4 vector.
// ---------------------------------------------------------------------------
__global__ __launch_bounds__(256) void dwconv_kernel(
    const unsigned short* __restrict__ x_in, const float* __restrict__ dwk,
    unsigned short* __restrict__ out)
{
    int i4 = blockIdx.x * 256 + threadIdx.x;
    if (i4 >= MM * DINNER / 4) return;
    int d = (i4 * 4) & (DINNER - 1);
    int bl = (i4 * 4) >> 11;
    int l = bl & (Ll - 1);
    int b = bl >> 11;
    float a0 = 0.f, a1 = 0.f, a2 = 0.f, a3 = 0.f;
#pragma unroll
    for (int k = 0; k < DCONV; ++k) {
        int t = l + k - (DCONV - 1);
        if (t >= 0) {
            ushort4 xv = *(const ushort4*)&x_in[(size_t)(b * Ll + t) * DINNER + d];
            float4 wv = *(const float4*)&dwk[k * DINNER + d];
            a0 = fmaf(bf2f(xv.x), wv.x, a0);
            a1 = fmaf(bf2f(xv.y), wv.y, a1);
            a2 = fmaf(bf2f(xv.z), wv.z, a2);
            a3 = fmaf(bf2f(xv.w), wv.w, a3);
        }
    }
    ushort4 o;
    o.x = f2bf(a0); o.y = f2bf(a1); o.z = f2bf(a2); o.w = f2bf(a3);
    *(ushort4*)&out[i4 * 4] = o;
}

// ---------------------------------------------------------------------------
// Selective scan pass 1: per-chunk local scan from h=0. xc is bf16.
// ---------------------------------------------------------------------------
__global__ __launch_bounds__(256) void scan_pass1(
    const float* __restrict__ delta, const unsigned short* __restrict__ xc,
    const float* __restrict__ xdbl, const float* __restrict__ A_log,
    float* __restrict__ cs_a, float* __restrict__ cs_h)
{
    const int d = blockIdx.x * 256 + threadIdx.x;
    const int c = blockIdx.y;
    const int b = blockIdx.z;
    const int t0 = c * CL;

    __shared__ float sB[CL][8];
    {
        int i = threadIdx.x;
        int t = i >> 3, j = i & 7;
        sB[t][j] = xdbl[((size_t)(b * Ll + t0 + t)) * 80 + DTRANK + j];
    }
    __syncthreads();

    float An[8];
#pragma unroll
    for (int n = 0; n < 8; ++n) An[n] = -__expf(A_log[d * 8 + n]);

    float h[8], ap[8];
#pragma unroll
    for (int n = 0; n < 8; ++n) { h[n] = 0.0f; ap[n] = 1.0f; }

    const float* dptr = delta + ((size_t)(b * Ll + t0)) * DINNER + d;
    const unsigned short* xptr = xc + ((size_t)(b * Ll + t0)) * DINNER + d;

#pragma unroll 4
    for (int t = 0; t < CL; ++t) {
        float dl = dptr[(size_t)t * DINNER];
        float xv = bf2f(xptr[(size_t)t * DINNER]);
        float du = dl * xv;
#pragma unroll
        for (int n = 0; n < 8; ++n) {
            float dA = __expf(dl * An[n]);
            h[n] = fmaf(dA, h[n], du * sB[t][n]);
            ap[n] *= dA;
        }
    }

    size_t base = (((size_t)(b * NCH + c)) * 8) * DINNER + d;
#pragma unroll
    for (int n = 0; n < 8; ++n) {
        cs_a[base + (size_t)n * DINNER] = ap[n];
        cs_h[base + (size_t)n * DINNER] = h[n];
    }
}

// Pass 2: sequential combine; hin ALIASES cs_h (in-place) — read-before-write.
__global__ __launch_bounds__(256) void scan_pass2(
    const float* __restrict__ cs_a, const float* cs_h, float* hin)
{
    int idx = blockIdx.x * 256 + threadIdx.x;
    if (idx >= Bb * 8 * DINNER) return;
    int d = idx & (DINNER - 1);
    int n = (idx >> 11) & 7;
    int b = idx >> 14;
    float H = 0.0f;
#pragma unroll 4
    for (int c = 0; c < NCH; ++c) {
        size_t o = (((size_t)(b * NCH + c)) * 8 + n) * DINNER + d;
        float a = cs_a[o];
        float hh = cs_h[o];
        hin[o] = H;
        H = fmaf(a, H, hh);
    }
}

// Pass 3: replay with correct h_in; fused epilogue -> bf16 y. z dense bf16.
__global__ __launch_bounds__(256) void scan_pass3(
    const float* __restrict__ delta, const unsigned short* __restrict__ xc,
    const float* __restrict__ xdbl, const float* __restrict__ A_log,
    const float* __restrict__ hin, const unsigned short* __restrict__ z,
    const float* __restrict__ Dvec, unsigned short* __restrict__ y_bf)
{
    const int d = blockIdx.x * 256 + threadIdx.x;
    const int c = blockIdx.y;
    const int b = blockIdx.z;
    const int t0 = c * CL;

    __shared__ float sB[CL][8];
    __shared__ float sC[CL][8];
    {
        int i = threadIdx.x;
        int t = i >> 4, j = i & 15;
        float v = xdbl[((size_t)(b * Ll + t0 + t)) * 80 + DTRANK + j];
        if (j < 8) sB[t][j] = v; else sC[t][j - 8] = v;
        t = (i + 256) >> 4; j = (i + 256) & 15;
        v = xdbl[((size_t)(b * Ll + t0 + t)) * 80 + DTRANK + j];
        if (j < 8) sB[t][j] = v; else sC[t][j - 8] = v;
    }
    __syncthreads();

    float An[8];
#pragma unroll
    for (int n = 0; n < 8; ++n) An[n] = -__expf(A_log[d * 8 + n]);

    float h[8];
    size_t hbase = (((size_t)(b * NCH + c)) * 8) * DINNER + d;
#pragma unroll
    for (int n = 0; n < 8; ++n) h[n] = hin[hbase + (size_t)n * DINNER];

    const float Dd = Dvec[d];
    const float* dptr = delta + ((size_t)(b * Ll + t0)) * DINNER + d;
    const unsigned short* xptr = xc + ((size_t)(b * Ll + t0)) * DINNER + d;
    const unsigned short* zptr = z + ((size_t)(b * Ll + t0)) * DINNER + d;
    unsigned short* yptr = y_bf + ((size_t)(b * Ll + t0)) * DINNER + d;

    for (int t = 0; t < CL; ++t) {
        float dl = dptr[(size_t)t * DINNER];
        float xv = bf2f(xptr[(size_t)t * DINNER]);
        float du = dl * xv;
        float yt = 0.0f;
#pragma unroll
        for (int n = 0; n < 8; ++n) {
            float dA = __expf(dl * An[n]);
            h[n] = fmaf(dA, h[n], du * sB[t][n]);
            yt = fmaf(sC[t][n], h[n], yt);
        }
        float zv = bf2f(zptr[(size_t)t * DINNER]);
        yptr[(size_t)t * DINNER] = f2bf((yt + xv * Dd) * silu_f(zv));
    }
}

// ---------------------------------------------------------------------------
extern "C" void kernel_launch(void* const* d_in, const int* in_sizes, int n_in,
                              void* d_out, int out_size, void* d_ws, size_t ws_size,
                              hipStream_t stream)
{
    const float* x         = (const float*)d_in[0];
    const float* W_in      = (const float*)d_in[1];
    const float* dwk       = (const float*)d_in[2];
    const float* pwk       = (const float*)d_in[3];
    const float* conv_bias = (const float*)d_in[4];
    const float* W_x       = (const float*)d_in[5];
    const float* W_dt      = (const float*)d_in[6];
    const float* b_dt      = (const float*)d_in[7];
    const float* A_log     = (const float*)d_in[8];
    const float* Dv        = (const float*)d_in[9];
    const float* W_out     = (const float*)d_in[10];
    float* out = (float*)d_out;

    // workspace map (MiB offsets; peak 152.25 MiB <= proven 154)
    char* ws = (char*)d_ws;
    unsigned short* x_in_bf = (unsigned short*)(ws);                  // [0,16)   G1..conv
    unsigned short* z_bf    = (unsigned short*)(ws + (16ull << 20));  // [16,32)  G1..p3
    float*          delta   = (float*)(ws + (32ull << 20));           // [32,64)  G4..p3
    unsigned short* x_bf    = (unsigned short*)(ws + (64ull << 20));  // [64,72)  prep..G1
    unsigned short* y_bf    = (unsigned short*)(ws + (64ull << 20));  // [64,80)  p3..G5
    unsigned short* Wint    = (unsigned short*)(ws + (72ull << 20));  // [72,80)  prep..G1
    unsigned short* pw_t    = (unsigned short*)(ws + (80ull << 20));  // [80,88)  prep..G2
    unsigned short* xcp_bf  = (unsigned short*)(ws + (88ull << 20));  // [88,104) conv..G2
    unsigned short* xc_bf   = (unsigned short*)(ws + (104ull << 20)); // [104,120) G2..p3
    unsigned short* Woutt   = (unsigned short*)(ws + (120ull << 20)); // [120,124) prep..G5
    float*          xdbl    = (float*)(ws + (124ull << 20));          // [124,125.25) g3red..p3
    unsigned short* xdbl64  = (unsigned short*)(ws + (125ull << 20) + (512ull << 10)); // 0.5 MB
    float*          g3part  = (float*)(ws + (126ull << 20));          // [126,136) g3..g3red
    float*          cs_a    = (float*)(ws + (136ull << 20));          // [136,144) p1..p2
    float*          cs_h    = (float*)(ws + (144ull << 20));          // [144,152) p1..p3
    unsigned short* Wdtt    = (unsigned short*)(ws + (152ull << 20)); // 0.25 MB, prep..G4
    float*          hin     = cs_h;   // in-place
    dim3 blk(256);

    // prep: cast + 4 transposes fused into one dispatch
    prep_all<<<14464, blk, 0, stream>>>(x, W_in, pwk, W_out, W_dt,
                                        x_bf, Wint, pw_t, Woutt, Wdtt);

    // G1: xz = x @ W_in, deinterleaved bf16 (x_in | z). 256^2-tile
    // deep-pipeline kernel (HW-verified r3/r6/r8), grid 16x16 = 1/CU.
    gemm256_g1<<<dim3((2 * DINNER) / 256, MM / 256), dim3(512), 0, stream>>>(
        x_bf, Wint, x_in_bf, z_bf,
        /*K*/DMODEL, /*lda*/DMODEL, /*ldb*/DMODEL, /*ldc*/DINNER,
        /*nsplit*/DINNER);

    // depthwise causal conv (bf16 in, bf16 out)
    dwconv_kernel<<<MM * DINNER / 4 / 256, blk, 0, stream>>>(x_in_bf, dwk, xcp_bf);

    // G2: xc = silu(conv @ pw + conv_bias) -> bf16. r9: 128x128-tile,
    // 4-wave counted-vmcnt 2-phase, 64 KB LDS -> 2 BLOCKS/CU (r8 was
    // 1 block/CU, MfmaUtil 28%, Occupancy 18% — lockstep waves idled the
    // CU at every phase-end vmcnt). Grid 16x32 = 512 = 2/CU, XCD 8x8.
    gemm128x128<1, unsigned short>
        <<<dim3(DINNER / 128, MM / 128), blk, 0, stream>>>(
        xcp_bf, pw_t, xc_bf,
        /*K*/DINNER, /*lda*/DINNER, /*ldb*/DINNER, /*ldc*/DINNER, conv_bias);

    // G3: x_dbl partials = xc @ W_x (split-K fp32) + materialized reduce
    g3_splitk<<<dim3(MM / 64, G3_KCH), blk, 0, stream>>>(xc_bf, W_x, g3part);
    g3_reduce<<<(MM * 80 / 4 + 255) / 256, blk, 0, stream>>>(g3part, xdbl, xdbl64);

    // G4: delta = softplus(xdbl64 @ Wdtt^T + b_dt) — MFMA, K=64. TN=64,
    // grid 32x32 = 1024 blocks = 4/CU (r8-verified; anomaly gone).
    mfma_gemm<2, 4, 64, float>
        <<<dim3(DINNER / 64, MM / 128), blk, 0, stream>>>(
        xdbl64, Wdtt, delta, delta, DINNER + 1,
        MM, DINNER, DTRANK, DTRANK, DTRANK, DINNER, b_dt);

    // selective scan, 3-pass chunked (CL=32, NCH=64 — proven)
    scan_pass1<<<dim3(DINNER / 256, NCH, Bb), blk, 0, stream>>>(
        delta, xc_bf, xdbl, A_log, cs_a, cs_h);
    scan_pass2<<<(Bb * 8 * DINNER + 255) / 256, blk, 0, stream>>>(cs_a, cs_h, hin);
    scan_pass3<<<dim3(DINNER / 256, NCH, Bb), blk, 0, stream>>>(
        delta, xc_bf, xdbl, A_log, hin, z_bf, Dv, y_bf);

    // G5: out = y @ W_out. NW=4, TN=64 -> 512 blocks, direct write,
    // + XCD region swizzle.
    mfma_gemm<0, 4, 64, float, 8, 8>
        <<<dim3(DMODEL / 64, MM / 128), blk, 0, stream>>>(
        y_bf, Woutt, out, out, DMODEL + 1,
        MM, DMODEL, DINNER, DINNER, DINNER, DMODEL, nullptr);
}